// Round 2
// baseline (2811.642 us; speedup 1.0000x reference)
//
#include <hip/hip_runtime.h>
#include <hip/hip_bf16.h>
#include <cstddef>

#define BD    2048
#define NF    32
#define DIMC  64
#define HEADS 8
#define DROW  2048
#define LNEPS 1e-5f

typedef __hip_bfloat16 bf16;
typedef __attribute__((ext_vector_type(8))) short short8;
typedef __attribute__((ext_vector_type(4))) float f32x4;

#define MFMA16 __builtin_amdgcn_mfma_f32_16x16x32_bf16

__device__ inline float ldin(const void* p, size_t i, int bf) {
    if (bf) return __bfloat162float(((const bf16*)p)[i]);
    return ((const float*)p)[i];
}

__device__ inline float gelu_exact(float x) {
    return 0.5f * x * (1.0f + erff(x * 0.70710678118654752f));
}

// ---------------- dtype detector ----------------
__global__ __launch_bounds__(64) void k_detect(const void* __restrict__ x,
                                               int* __restrict__ flag) {
    int i = threadIdx.x;
    size_t idx = (size_t)(2 * i) * 16384;
    unsigned short u = ((const unsigned short*)x)[idx];
    int e = (u >> 7) & 0xFF;
    int plausible = (e == 0) || (e >= 96 && e <= 132);
    unsigned long long m = __ballot(plausible);
    if (i == 0) *flag = (__popcll(m) >= 48) ? 1 : 0;
}

// ---------------- concat ----------------
__global__ __launch_bounds__(256) void k_concat(const void* __restrict__ x,
                                                const void* __restrict__ xc,
                                                float* __restrict__ X,
                                                const int* __restrict__ flag) {
    const int bf = *flag;
    int i = blockIdx.x * 256 + threadIdx.x;
    int d = i & 63;
    int f = (i >> 6) & 31;
    int b = i >> 11;
    float v = (f < 16) ? ldin(x,  ((size_t)b * 16 + f) * 64 + d, bf)
                       : ldin(xc, ((size_t)b * 16 + (f - 16)) * 64 + d, bf);
    X[i] = v;
}

// ---------------- LayerNorm 64 (fp32 + bf16 out) ----------------
__global__ __launch_bounds__(256) void k_ln64(const float* __restrict__ in,
                                              float* __restrict__ out,
                                              bf16* __restrict__ outh,
                                              const void* __restrict__ g,
                                              const void* __restrict__ b,
                                              size_t eoff,
                                              const int* __restrict__ flag) {
    const int bf = *flag;
    int row  = blockIdx.x * 4 + (threadIdx.x >> 6);
    int lane = threadIdx.x & 63;
    float v = in[(size_t)row * 64 + lane];
    float s = v;
    #pragma unroll
    for (int off = 32; off; off >>= 1) s += __shfl_xor(s, off);
    float mean = s * (1.0f / 64.0f);
    float dx = v - mean;
    float s2 = dx * dx;
    #pragma unroll
    for (int off = 32; off; off >>= 1) s2 += __shfl_xor(s2, off);
    float inv = rsqrtf(s2 * (1.0f / 64.0f) + LNEPS);
    float o = dx * inv * ldin(g, eoff + lane, bf) + ldin(b, eoff + lane, bf);
    out[(size_t)row * 64 + lane]  = o;
    outh[(size_t)row * 64 + lane] = __float2bfloat16(o);
}

// ---------------- LayerNorm 2048 (fp32 + bf16 out) ----------------
__global__ __launch_bounds__(256) void k_ln_row(const float* __restrict__ in,
                                                float* __restrict__ out,
                                                bf16* __restrict__ outh,
                                                const void* __restrict__ g,
                                                const void* __restrict__ b,
                                                size_t eoff,
                                                const int* __restrict__ flag) {
    const int bf = *flag;
    const int row = blockIdx.x, tid = threadIdx.x;
    __shared__ float red[4];
    const float* r = in + (size_t)row * DROW;
    float v[8];
    float s = 0.f;
    #pragma unroll
    for (int i = 0; i < 8; ++i) { v[i] = r[tid + i * 256]; s += v[i]; }
    #pragma unroll
    for (int off = 32; off; off >>= 1) s += __shfl_xor(s, off);
    if ((tid & 63) == 0) red[tid >> 6] = s;
    __syncthreads();
    float mean = (red[0] + red[1] + red[2] + red[3]) * (1.0f / DROW);
    __syncthreads();
    float s2 = 0.f;
    #pragma unroll
    for (int i = 0; i < 8; ++i) { float dx = v[i] - mean; s2 += dx * dx; }
    #pragma unroll
    for (int off = 32; off; off >>= 1) s2 += __shfl_xor(s2, off);
    if ((tid & 63) == 0) red[tid >> 6] = s2;
    __syncthreads();
    float inv = rsqrtf((red[0] + red[1] + red[2] + red[3]) * (1.0f / DROW) + LNEPS);
    #pragma unroll
    for (int i = 0; i < 8; ++i) {
        int j = tid + i * 256;
        float o = (v[i] - mean) * inv * ldin(g, eoff + j, bf) + ldin(b, eoff + j, bf);
        out[(size_t)row * DROW + j]  = o;
        outh[(size_t)row * DROW + j] = __float2bfloat16(o);
    }
}

// ---------------- transpose+cast weight ----------------
__global__ __launch_bounds__(256) void k_castT(const void* __restrict__ in, size_t eoff,
                                               int R, int C,
                                               bf16* __restrict__ out,
                                               const int* __restrict__ flag) {
    const int bf = *flag;
    __shared__ bf16 tile[32][33];
    const int tx = threadIdx.x & 31, ty = threadIdx.x >> 5;
    const int bx = blockIdx.x, by = blockIdx.y;
    #pragma unroll
    for (int k = 0; k < 4; ++k) {
        int r = bx * 32 + ty + k * 8;
        int c = by * 32 + tx;
        tile[ty + k * 8][tx] = __float2bfloat16(ldin(in, eoff + (size_t)r * C + c, bf));
    }
    __syncthreads();
    #pragma unroll
    for (int k = 0; k < 4; ++k) {
        int oc = by * 32 + ty + k * 8;
        int orr = bx * 32 + tx;
        out[(size_t)oc * R + orr] = tile[tx][ty + k * 8];
    }
}

// ---------------- transpose bf16 ----------------
__global__ __launch_bounds__(256) void k_transpose_bf(const bf16* __restrict__ in, int ld,
                                                      int R, int C,
                                                      bf16* __restrict__ out) {
    __shared__ bf16 tile[32][33];
    const int tx = threadIdx.x & 31, ty = threadIdx.x >> 5;
    const int bx = blockIdx.x, by = blockIdx.y;
    #pragma unroll
    for (int k = 0; k < 4; ++k) {
        int r = bx * 32 + ty + k * 8;
        int c = by * 32 + tx;
        tile[ty + k * 8][tx] = in[(size_t)r * ld + c];
    }
    __syncthreads();
    #pragma unroll
    for (int k = 0; k < 4; ++k) {
        int oc = by * 32 + ty + k * 8;
        int orr = bx * 32 + tx;
        out[(size_t)oc * R + orr] = tile[tx][ty + k * 8];
    }
}

// ---------------- MFMA GEMM (full-K, epilogue fused) ----------------
template <int WM, int WN, bool OBF>
__global__ __launch_bounds__(256) void k_mfma(
    int M, int N, int K,
    const bf16* __restrict__ A, int lda, long long sA,
    const bf16* __restrict__ Bt, int ldb, long long sB,
    void* __restrict__ C, int ldc, long long sC,
    float alpha,
    const void* __restrict__ bias, size_t biasOff,
    const float* __restrict__ addend, int ldadd,
    const int* __restrict__ flag)
{
    constexpr int TM = WM * 64, TN = WN * 64;
    const int z = blockIdx.z;
    A  += (size_t)z * sA;
    Bt += (size_t)z * sB;
    const int m0 = blockIdx.y * TM, n0 = blockIdx.x * TN;
    const int tid = threadIdx.x, lane = tid & 63, wave = tid >> 6;
    const int wy = wave / WN, wx = wave % WN;
    __shared__ short As[TM][72];
    __shared__ short Bs[TN][72];
    f32x4 acc[4][4] = {};
    const int row8 = tid >> 3, chunk = (tid & 7) * 8;
    for (int k0 = 0; k0 < K; k0 += 64) {
        #pragma unroll
        for (int i = 0; i < TM / 32; ++i) {
            int r = i * 32 + row8;
            *(short8*)&As[r][chunk] =
                *(const short8*)(A + (size_t)(m0 + r) * lda + k0 + chunk);
        }
        #pragma unroll
        for (int i = 0; i < TN / 32; ++i) {
            int r = i * 32 + row8;
            *(short8*)&Bs[r][chunk] =
                *(const short8*)(Bt + (size_t)(n0 + r) * ldb + k0 + chunk);
        }
        __syncthreads();
        #pragma unroll
        for (int ks = 0; ks < 64; ks += 32) {
            short8 af[4], bfr[4];
            #pragma unroll
            for (int mt = 0; mt < 4; ++mt)
                af[mt] = *(const short8*)&As[wy * 64 + mt * 16 + (lane & 15)][ks + (lane >> 4) * 8];
            #pragma unroll
            for (int nt = 0; nt < 4; ++nt)
                bfr[nt] = *(const short8*)&Bs[wx * 64 + nt * 16 + (lane & 15)][ks + (lane >> 4) * 8];
            #pragma unroll
            for (int mt = 0; mt < 4; ++mt)
                #pragma unroll
                for (int nt = 0; nt < 4; ++nt)
                    acc[mt][nt] = MFMA16(af[mt], bfr[nt], acc[mt][nt], 0, 0, 0);
        }
        __syncthreads();
    }
    const int bfl = bias ? *flag : 0;
    #pragma unroll
    for (int mt = 0; mt < 4; ++mt) {
        #pragma unroll
        for (int r = 0; r < 4; ++r) {
            int m = m0 + wy * 64 + mt * 16 + (lane >> 4) * 4 + r;
            #pragma unroll
            for (int nt = 0; nt < 4; ++nt) {
                int n = n0 + wx * 64 + nt * 16 + (lane & 15);
                float v = acc[mt][nt][r] * alpha;
                if (bias)   v += ldin(bias, biasOff + n, bfl);
                if (addend) v += addend[(size_t)m * ldadd + n];
                size_t idx = (size_t)z * sC + (size_t)m * ldc + n;
                if constexpr (OBF) ((bf16*)C)[idx] = __float2bfloat16(v);
                else               ((float*)C)[idx] = v;
            }
        }
    }
}

// ---------------- MFMA GEMM split-K: z = K-chunk, fp32 partials ----------------
template <int WM, int WN>
__global__ __launch_bounds__(256) void k_mfma_sk(
    int M, int N, int KC,
    const bf16* __restrict__ A, int lda,
    const bf16* __restrict__ Bt, int ldb,
    float* __restrict__ Cp, long long pstride)
{
    constexpr int TM = WM * 64, TN = WN * 64;
    const int z = blockIdx.z;
    const int m0 = blockIdx.y * TM, n0 = blockIdx.x * TN;
    const int tid = threadIdx.x, lane = tid & 63, wave = tid >> 6;
    const int wy = wave / WN, wx = wave % WN;
    __shared__ short As[TM][72];
    __shared__ short Bs[TN][72];
    f32x4 acc[4][4] = {};
    const int row8 = tid >> 3, chunk = (tid & 7) * 8;
    const int kend = z * KC + KC;
    for (int k0 = z * KC; k0 < kend; k0 += 64) {
        #pragma unroll
        for (int i = 0; i < TM / 32; ++i) {
            int r = i * 32 + row8;
            *(short8*)&As[r][chunk] =
                *(const short8*)(A + (size_t)(m0 + r) * lda + k0 + chunk);
        }
        #pragma unroll
        for (int i = 0; i < TN / 32; ++i) {
            int r = i * 32 + row8;
            *(short8*)&Bs[r][chunk] =
                *(const short8*)(Bt + (size_t)(n0 + r) * ldb + k0 + chunk);
        }
        __syncthreads();
        #pragma unroll
        for (int ks = 0; ks < 64; ks += 32) {
            short8 af[4], bfr[4];
            #pragma unroll
            for (int mt = 0; mt < 4; ++mt)
                af[mt] = *(const short8*)&As[wy * 64 + mt * 16 + (lane & 15)][ks + (lane >> 4) * 8];
            #pragma unroll
            for (int nt = 0; nt < 4; ++nt)
                bfr[nt] = *(const short8*)&Bs[wx * 64 + nt * 16 + (lane & 15)][ks + (lane >> 4) * 8];
            #pragma unroll
            for (int mt = 0; mt < 4; ++mt)
                #pragma unroll
                for (int nt = 0; nt < 4; ++nt)
                    acc[mt][nt] = MFMA16(af[mt], bfr[nt], acc[mt][nt], 0, 0, 0);
        }
        __syncthreads();
    }
    float* Co = Cp + (size_t)z * pstride;
    #pragma unroll
    for (int mt = 0; mt < 4; ++mt)
        #pragma unroll
        for (int r = 0; r < 4; ++r) {
            int m = m0 + wy * 64 + mt * 16 + (lane >> 4) * 4 + r;
            #pragma unroll
            for (int nt = 0; nt < 4; ++nt) {
                int n = n0 + wx * 64 + nt * 16 + (lane & 15);
                Co[(size_t)m * N + n] = acc[mt][nt][r];
            }
        }
}

// ---------------- MFMA GEMM split-K ATOMIC: z-chunks accumulate into fp32 C ----------------
// C must be pre-initialized (bias + optional addend) by an init dispatch.
// unsafeAtomicAdd -> global_atomic_add_f32 (no return, fire-and-forget into L2/L3).
template <int WM, int WN>
__global__ __launch_bounds__(256) void k_mfma_at(
    int M, int N, int KC,
    const bf16* __restrict__ A, int lda,
    const bf16* __restrict__ Bt, int ldb,
    float* __restrict__ C)
{
    constexpr int TM = WM * 64, TN = WN * 64;
    const int z = blockIdx.z;
    const int m0 = blockIdx.y * TM, n0 = blockIdx.x * TN;
    const int tid = threadIdx.x, lane = tid & 63, wave = tid >> 6;
    const int wy = wave / WN, wx = wave % WN;
    __shared__ short As[TM][72];
    __shared__ short Bs[TN][72];
    f32x4 acc[4][4] = {};
    const int row8 = tid >> 3, chunk = (tid & 7) * 8;
    const int kend = z * KC + KC;
    for (int k0 = z * KC; k0 < kend; k0 += 64) {
        #pragma unroll
        for (int i = 0; i < TM / 32; ++i) {
            int r = i * 32 + row8;
            *(short8*)&As[r][chunk] =
                *(const short8*)(A + (size_t)(m0 + r) * lda + k0 + chunk);
        }
        #pragma unroll
        for (int i = 0; i < TN / 32; ++i) {
            int r = i * 32 + row8;
            *(short8*)&Bs[r][chunk] =
                *(const short8*)(Bt + (size_t)(n0 + r) * ldb + k0 + chunk);
        }
        __syncthreads();
        #pragma unroll
        for (int ks = 0; ks < 64; ks += 32) {
            short8 af[4], bfr[4];
            #pragma unroll
            for (int mt = 0; mt < 4; ++mt)
                af[mt] = *(const short8*)&As[wy * 64 + mt * 16 + (lane & 15)][ks + (lane >> 4) * 8];
            #pragma unroll
            for (int nt = 0; nt < 4; ++nt)
                bfr[nt] = *(const short8*)&Bs[wx * 64 + nt * 16 + (lane & 15)][ks + (lane >> 4) * 8];
            #pragma unroll
            for (int mt = 0; mt < 4; ++mt)
                #pragma unroll
                for (int nt = 0; nt < 4; ++nt)
                    acc[mt][nt] = MFMA16(af[mt], bfr[nt], acc[mt][nt], 0, 0, 0);
        }
        __syncthreads();
    }
    #pragma unroll
    for (int mt = 0; mt < 4; ++mt)
        #pragma unroll
        for (int r = 0; r < 4; ++r) {
            int m = m0 + wy * 64 + mt * 16 + (lane >> 4) * 4 + r;
            #pragma unroll
            for (int nt = 0; nt < 4; ++nt) {
                int n = n0 + wx * 64 + nt * 16 + (lane & 15);
                unsafeAtomicAdd(&C[(size_t)m * N + n], acc[mt][nt][r]);
            }
        }
}

// ---------------- split-K combine: out = sum partials (+bias)(+addend) ----------------
// Also used with KS=0 / P=nullptr as the INIT kernel for atomic GEMMs
// (writes bias + addend only).
template <bool OBF>
__global__ __launch_bounds__(256) void k_combine(
    int KS, const float* __restrict__ P, long long pstride, int N,
    void* __restrict__ C,
    const void* __restrict__ bias, size_t biasOff,
    const float* __restrict__ addend,
    const int* __restrict__ flag)
{
    int i = blockIdx.x * 256 + threadIdx.x;
    float v = 0.f;
    for (int z = 0; z < KS; ++z) v += P[(size_t)z * pstride + i];
    if (bias)   v += ldin(bias, biasOff + (size_t)(i % N), bias ? *flag : 0);
    if (addend) v += addend[i];
    if constexpr (OBF) ((bf16*)C)[i] = __float2bfloat16(v);
    else               ((float*)C)[i] = v;
}

// ---------------- QKV projection sub-tile: c += X(32x64) @ W_h(64x64) ----------------
__device__ inline void proj_tile(const short8 xa[2][2], const bf16* __restrict__ wbase,
                                 int l15, int quad, f32x4 c[2][4]) {
    #pragma unroll
    for (int nt = 0; nt < 4; ++nt) {
        short8 b0 = *(const short8*)(wbase + (size_t)(nt * 16 + l15) * 64 + quad * 8);
        short8 b1 = *(const short8*)(wbase + (size_t)(nt * 16 + l15) * 64 + 32 + quad * 8);
        #pragma unroll
        for (int mt = 0; mt < 2; ++mt) {
            c[mt][nt] = MFMA16(xa[mt][0], b0, c[mt][nt], 0, 0, 0);
            c[mt][nt] = MFMA16(xa[mt][1], b1, c[mt][nt], 0, 0, 0);
        }
    }
}

// ---------------- fused col QKV-proj + attention (per-wave LDS, 2-buffer, no barriers) ----------------
// Softmax: logits are bounded (LN'd activations x 0.02-scale weights -> |logit| <~ 2),
// so the max-subtraction pass is skipped: P = exp(l) stored UNNORMALIZED; O is scaled
// by 1/rowsum after PV (rowsum lane-alignment matches O's C-layout rows).
__global__ __launch_bounds__(256) void k_col_qkv_attn(
    const bf16* __restrict__ Xh, const bf16* __restrict__ Wt,
    bf16* __restrict__ Oh)
{
    __shared__ __align__(16) short bufA[4][2304];   // Q (32x72) -> P
    __shared__ __align__(16) short bufB[4][2304];   // K (32x72) -> V^T (64x36)
    const int tid = threadIdx.x, lane = tid & 63, wave = tid >> 6;
    const int task = blockIdx.x * 4 + wave;   // sample*8 + head
    const int s = task >> 3, h = task & 7;
    const int l15 = lane & 15, quad = lane >> 4;
    short* A  = bufA[wave];
    short* Bb = bufB[wave];

    short8 xa[2][2];
    #pragma unroll
    for (int mt = 0; mt < 2; ++mt)
        #pragma unroll
        for (int kc = 0; kc < 2; ++kc)
            xa[mt][kc] = *(const short8*)(Xh + (size_t)(s * 32 + mt * 16 + l15) * 64 + kc * 32 + quad * 8);

    // ---- Q -> A (C-layout, stride 72) ----
    {
        f32x4 c[2][4] = {};
        proj_tile(xa, Wt + (size_t)(h * 64) * 64, l15, quad, c);
        #pragma unroll
        for (int mt = 0; mt < 2; ++mt)
            #pragma unroll
            for (int nt = 0; nt < 4; ++nt)
                #pragma unroll
                for (int r = 0; r < 4; ++r)
                    *(bf16*)&A[(mt * 16 + quad * 4 + r) * 72 + nt * 16 + l15] =
                        __float2bfloat16(c[mt][nt][r]);
    }
    // ---- K -> Bb (C-layout, stride 72) ----
    {
        f32x4 c[2][4] = {};
        proj_tile(xa, Wt + (size_t)(512 + h * 64) * 64, l15, quad, c);
        #pragma unroll
        for (int mt = 0; mt < 2; ++mt)
            #pragma unroll
            for (int nt = 0; nt < 4; ++nt)
                #pragma unroll
                for (int r = 0; r < 4; ++r)
                    *(bf16*)&Bb[(mt * 16 + quad * 4 + r) * 72 + nt * 16 + l15] =
                        __float2bfloat16(c[mt][nt][r]);
    }
    // ---- S = Q @ K^T ----
    f32x4 S[2][2] = {};
    #pragma unroll
    for (int mt = 0; mt < 2; ++mt) {
        short8 qa0 = *(const short8*)&A[(mt * 16 + l15) * 72 + quad * 8];
        short8 qa1 = *(const short8*)&A[(mt * 16 + l15) * 72 + 32 + quad * 8];
        #pragma unroll
        for (int nt = 0; nt < 2; ++nt) {
            short8 kb0 = *(const short8*)&Bb[(nt * 16 + l15) * 72 + quad * 8];
            short8 kb1 = *(const short8*)&Bb[(nt * 16 + l15) * 72 + 32 + quad * 8];
            S[mt][nt] = MFMA16(qa0, kb0, S[mt][nt], 0, 0, 0);
            S[mt][nt] = MFMA16(qa1, kb1, S[mt][nt], 0, 0, 0);
        }
    }
    // ---- V -> Bb transposed ([64][36]; K dead after S) ----
    {
        f32x4 c[2][4] = {};
        proj_tile(xa, Wt + (size_t)(1024 + h * 64) * 64, l15, quad, c);
        #pragma unroll
        for (int mt = 0; mt < 2; ++mt)
            #pragma unroll
            for (int nt = 0; nt < 4; ++nt)
                #pragma unroll
                for (int r = 0; r < 4; ++r)
                    *(bf16*)&Bb[(nt * 16 + l15) * 36 + mt * 16 + quad * 4 + r] =
                        __float2bfloat16(c[mt][nt][r]);
    }
    // ---- no-max softmax; unnormalized P -> A (Q dead); keep 1/rowsum ----
    float inv[2][4];
    #pragma unroll
    for (int mt = 0; mt < 2; ++mt) {
        #pragma unroll
        for (int ri = 0; ri < 4; ++ri) {
            float e0 = __expf(S[mt][0][ri] * 0.125f);
            float e1 = __expf(S[mt][1][ri] * 0.125f);
            float sum = e0 + e1;
            #pragma unroll
            for (int msk = 1; msk < 16; msk <<= 1) sum += __shfl_xor(sum, msk);
            inv[mt][ri] = 1.0f / sum;
            int row = mt * 16 + quad * 4 + ri;
            *(bf16*)&A[row * 72 + l15]      = __float2bfloat16(e0);
            *(bf16*)&A[row * 72 + 16 + l15] = __float2bfloat16(e1);
        }
    }
    // ---- O = P @ V, then normalize ----
    short8 pa[2];
    #pragma unroll
    for (int mt = 0; mt < 2; ++mt)
        pa[mt] = *(const short8*)&A[(mt * 16 + l15) * 72 + quad * 8];
    f32x4 O[2][4] = {};
    #pragma unroll
    for (int nt = 0; nt < 4; ++nt) {
        short8 vb = *(const short8*)&Bb[(nt * 16 + l15) * 36 + quad * 8];
        #pragma unroll
        for (int mt = 0; mt < 2; ++mt)
            O[mt][nt] = MFMA16(pa[mt], vb, O[mt][nt], 0, 0, 0);
    }
    #pragma unroll
    for (int mt = 0; mt < 2; ++mt)
        #pragma unroll
        for (int nt = 0; nt < 4; ++nt)
            #pragma unroll
            for (int ri = 0; ri < 4; ++ri) {
                size_t row = (size_t)s * 32 + mt * 16 + quad * 4 + ri;
                Oh[row * 512 + h * 64 + nt * 16 + l15] =
                    __float2bfloat16(O[mt][nt][ri] * inv[mt][ri]);
            }
}

// ---------------- flash row attention v2: K-split, barrier-free ----------------
__global__ __launch_bounds__(256) void k_flash_row(
    const bf16* __restrict__ QKV, const bf16* __restrict__ Vt,
    float* __restrict__ Opart, float* __restrict__ ML)
{
    __shared__ __align__(16) short Ps[4][16][136];
    const int tid = threadIdx.x, lane = tid & 63, wave = tid >> 6;
    const int h = blockIdx.y, z = blockIdx.z;
    const int q0 = blockIdx.x * 64 + wave * 16;
    const int l15 = lane & 15, quad = lane >> 4;

    short8 qa[2];
    #pragma unroll
    for (int kc = 0; kc < 2; ++kc)
        qa[kc] = *(const short8*)(QKV + (size_t)(q0 + l15) * 1536 + h * 64 + kc * 32 + quad * 8);

    float mi[4], li[4];
    #pragma unroll
    for (int r = 0; r < 4; ++r) { mi[r] = -1e30f; li[r] = 0.f; }
    f32x4 Oa[4] = {};

    #pragma unroll
    for (int jj = 0; jj < 4; ++jj) {
        const int j = z * 4 + jj;
        f32x4 s[8] = {};
        #pragma unroll
        for (int nt = 0; nt < 8; ++nt) {
            const bf16* krow = QKV + (size_t)(j * 128 + nt * 16 + l15) * 1536 + 512 + h * 64;
            short8 kb0 = *(const short8*)(krow + quad * 8);
            short8 kb1 = *(const short8*)(krow + 32 + quad * 8);
            s[nt] = MFMA16(qa[0], kb0, s[nt], 0, 0, 0);
            s[nt] = MFMA16(qa[1], kb1, s[nt], 0, 0, 0);
        }
        #pragma unroll
        for (int r = 0; r < 4; ++r) {
            float mt = -1e30f;
            #pragma unroll
            for (int nt = 0; nt < 8; ++nt) { s[nt][r] *= 0.125f; mt = fmaxf(mt, s[nt][r]); }
            #pragma unroll
            for (int msk = 1; msk < 16; msk <<= 1) mt = fmaxf(mt, __shfl_xor(mt, msk));
            float mn = fmaxf(mi[r], mt);
            float alpha = __expf(mi[r] - mn);
            float ls = 0.f;
            #pragma unroll
            for (int nt = 0; nt < 8; ++nt) { float p = __expf(s[nt][r] - mn); s[nt][r] = p; ls += p; }
            #pragma unroll
            for (int msk = 1; msk < 16; msk <<= 1) ls += __shfl_xor(ls, msk);
            li[r] = li[r] * alpha + ls;
            mi[r] = mn;
            #pragma unroll
            for (int nt = 0; nt < 4; ++nt) Oa[nt][r] *= alpha;
            int row = quad * 4 + r;
            #pragma unroll
            for (int nt = 0; nt < 8; ++nt)
                *(bf16*)&Ps[wave][row][nt * 16 + l15] = __float2bfloat16(s[nt][r]);
        }
        short8 pa[4];
        #pragma unroll
        for (int kc = 0; kc < 4; ++kc)
            pa[kc] = *(const short8*)&Ps[wave][l15][kc * 32 + quad * 8];
        #pragma unroll
        for (int nt = 0; nt < 4; ++nt) {
            #pragma unroll
            for (int kc = 0; kc < 4; ++kc) {
                short8 vb = *(const short8*)(Vt + (size_t)(h * 64 + nt * 16 + l15) * 2048 +
                                             j * 128 + kc * 32 + quad * 8);
                Oa[nt] = MFMA16(pa[kc], vb, Oa[nt], 0, 0, 0);
            }
        }
    }
    float* Op = Opart + (size_t)z * 1048576;
    #pragma unroll
    for (int nt = 0; nt < 4; ++nt)
        #pragma unroll
        for (int r = 0; r < 4; ++r)
            Op[(size_t)(q0 + quad * 4 + r) * 512 + h * 64 + nt * 16 + l15] = Oa[nt][r];
    if (l15 == 0) {
        #pragma unroll
        for (int r = 0; r < 4; ++r) {
            int row = q0 + quad * 4 + r;
            ML[((size_t)(z * 8 + h) * 2048 + row) * 2]     = mi[r];
            ML[((size_t)(z * 8 + h) * 2048 + row) * 2 + 1] = li[r];
        }
    }
}

// ---------------- flash combine ----------------
__global__ __launch_bounds__(256) void k_flash_combine(
    const float* __restrict__ Opart, const float* __restrict__ ML,
    bf16* __restrict__ O)
{
    int i = blockIdx.x * 256 + threadIdx.x;     // 2048*512
    int row = i >> 9, n = i & 511, h = n >> 6;
    float m[4], l[4], M = -1e30f;
    #pragma unroll
    for (int z = 0; z < 4; ++z) {
        m[z] = ML[((size_t)(z * 8 + h) * 2048 + row) * 2];
        l[z] = ML[((size_t)(z * 8 + h) * 2048 + row) * 2 + 1];
        M = fmaxf(M, m[z]);
    }
    float num = 0.f, den = 0.f;
    #pragma unroll
    for (int z = 0; z < 4; ++z) {
        float w = __expf(m[z] - M);
        num += w * Opart[(size_t)z * 1048576 + i];
        den += w * l[z];
    }
    O[i] = __float2bfloat16(num / den);
}

// ---------------- GEGLU row ----------------
__global__ __launch_bounds__(256) void k_geglu_row(const float* __restrict__ H,
                                                   bf16* __restrict__ P) {
    int i = blockIdx.x * 256 + threadIdx.x;
    int r = i >> 10, j = i & 1023;
    float a = H[(size_t)r * 2048 + j];
    float g = H[(size_t)r * 2048 + 1024 + j];
    P[i] = __float2bfloat16(a * gelu_exact(g));
}

// ---------------- GEGLU col ----------------
__global__ __launch_bounds__(256) void k_geglu_col(const bf16* __restrict__ H,
                                                   bf16* __restrict__ P) {
    int i = blockIdx.x * 256 + threadIdx.x;
    int r = i >> 8, j = i & 255;
    float a = __bfloat162float(H[(size_t)r * 512 + j]);
    float g = __bfloat162float(H[(size_t)r * 512 + 256 + j]);
    P[i] = __float2bfloat16(a * gelu_exact(g));
}

// ---------------- final cast ----------------
__global__ __launch_bounds__(256) void k_cast_out(const float* __restrict__ X,
                                                  void* __restrict__ out,
                                                  const int* __restrict__ flag) {
    const int bf = *flag;
    int i = blockIdx.x * 256 + threadIdx.x;
    if (bf) ((bf16*)out)[i] = __float2bfloat16(X[i]);
    else    ((float*)out)[i] = X[i];
}

// =====================================================================
extern "C" void kernel_launch(void* const* d_in, const int* in_sizes, int n_in,
                              void* d_out, int out_size, void* d_ws, size_t ws_size,
                              hipStream_t stream) {
    const void* x       = d_in[0];
    const void* x_cont  = d_in[1];
    const void* c_ln1_g = d_in[2];
    const void* c_ln1_b = d_in[3];
    const void* c_wqkv  = d_in[4];
    const void* c_wo_w  = d_in[5];
    const void* c_wo_b  = d_in[6];
    const void* c_ln2_g = d_in[7];
    const void* c_ln2_b = d_in[8];
    const void* c_w1    = d_in[9];
    const void* c_b1    = d_in[10];
    const void* c_w2    = d_in[11];
    const void* c_b2    = d_in[12];
    const void* r_ln1_g = d_in[13];
    const void* r_ln1_b = d_in[14];
    const void* r_wqkv  = d_in[15];
    const void* r_wo_w  = d_in[16];
    const void* r_wo_b  = d_in[17];
    const void* r_ln2_g = d_in[18];
    const void* r_ln2_b = d_in[19];
    const void* r_w1    = d_in[20];
    const void* r_b1    = d_in[21];
    const void* r_w2    = d_in[22];
    const void* r_b2    = d_in[23];

    const size_t NX = (size_t)BD * NF * DIMC;        // 4,194,304
    float* X   = (float*)d_ws;
    float* XN  = X   + NX;
    float* ACC = XN  + NX;
    bf16* XNh  = (bf16*)(ACC + NX);
    bf16* WtR  = XNh + NX;                            // <=2048x2048
    bf16* WcQ  = WtR + (size_t)2048 * 2048;           // 1536x64
    bf16* WcO  = WcQ + 98304;                         // 64x512
    bf16* Wc1  = WcO + 32768;                         // 512x64
    bf16* Wc2  = Wc1 + 32768;                         // 64x256
    bf16* Sc   = Wc2 + 16384;                         // scratch union base

    // col block overlays:
    bf16*  OhC  = Sc;                                         // [0, 64 MiB)
    bf16*  H1   = Sc;                                         // [0, 64 MiB) (OhC dead)
    bf16*  Pc   = Sc + 33554432;                              // [64, 96 MiB)
    // row block overlays:
    bf16*  QKVhR = Sc;                                        // 6.3MB
    bf16*  VtR   = QKVhR + 3145728;                           // 2.1MB
    bf16*  OhR   = VtR + 1048576;                             // 2.1MB
    bf16*  PmR   = OhR + 1048576;                             // 4.2MB
    float* Hrow  = (float*)(PmR + 2097152);                   // 16.8MB (ends 31.5MB)
    float* GpR   = (float*)((char*)Sc + 33554432);            // r_wqkv partials (ends 96 MiB)
    float* MLp   = GpR + (size_t)4 * 1048576;                 // flash m/l (1MB)

    char* scEnd = (char*)Sc + 100663296;                      // 96 MiB
    int*  flag  = (int*)scEnd;
    const size_t need = (size_t)(scEnd + 64 - (char*)d_ws);
    if (ws_size < need) return;

    k_detect<<<1, 64, 0, stream>>>(x, flag);
    k_concat<<<16384, 256, 0, stream>>>(x, x_cont, X, flag);

    for (int d = 0; d < 4; ++d) {
        // ================= col block =================
        k_ln64<<<16384, 256, 0, stream>>>(X, XN, XNh, c_ln1_g, c_ln1_b, (size_t)d * 64, flag);
        k_castT<<<dim3(2, 48), 256, 0, stream>>>(c_wqkv, (size_t)d * 64 * 1536, 64, 1536, WcQ, flag);
        k_col_qkv_attn<<<4096, 256, 0, stream>>>(XNh, WcQ, OhC);
        // ACC = OhC @ c_wo_w + c_wo_b + XN  (init + atomic split-K=2)
        k_castT<<<dim3(16, 2), 256, 0, stream>>>(c_wo_w, (size_t)d * 512 * 64, 512, 64, WcO, flag);
        k_combine<false><<<16384, 256, 0, stream>>>(
            0, nullptr, 0, 64, ACC, c_wo_b, (size_t)d * 64, XN, flag);
        k_mfma_at<4, 1><<<dim3(1, 256, 2), 256, 0, stream>>>(
            65536, 64, 256, OhC, 512, WcO, 512, ACC);
        k_ln64<<<16384, 256, 0, stream>>>(ACC, XN, XNh, c_ln2_g, c_ln2_b, (size_t)d * 64, flag);
        // H1 = XNh @ c_w1 + c_b1
        k_castT<<<dim3(2, 16), 256, 0, stream>>>(c_w1, (size_t)d * 64 * 512, 64, 512, Wc1, flag);
        k_mfma<2, 2, true><<<dim3(4, 512, 1), 256, 0, stream>>>(
            65536, 512, 64, XNh, 64, 0, Wc1, 64, 0,
            H1, 512, 0, 1.0f, c_b1, (size_t)d * 512, nullptr, 0, flag);
        k_geglu_col<<<65536, 256, 0, stream>>>(H1, Pc);
        // X = Pc @ c_w2 + c_b2 + XN  (init + atomic split-K=4)
        k_castT<<<dim3(8, 2), 256, 0, stream>>>(c_w2, (size_t)d * 256 * 64, 256, 64, Wc2, flag);
        k_combine<false><<<16384, 256, 0, stream>>>(
            0, nullptr, 0, 64, X, c_b2, (size_t)d * 64, XN, flag);
        k_mfma_at<4, 1><<<dim3(1, 256, 4), 256, 0, stream>>>(
            65536, 64, 64, Pc, 256, Wc2, 256, X);

        // ================= row block =================
        k_ln_row<<<BD, 256, 0, stream>>>(X, XN, XNh, r_ln1_g, r_ln1_b, (size_t)d * DROW, flag);
        // QKVhR = XNh @ r_wqkv  (split-K=4, bf16 out -> keep combine)
        k_castT<<<dim3(64, 48), 256, 0, stream>>>(r_wqkv, (size_t)d * 2048 * 1536, 2048, 1536, WtR, flag);
        k_mfma_sk<2, 2><<<dim3(12, 16, 4), 256, 0, stream>>>(
            2048, 1536, 512, XNh, 2048, WtR, 2048, GpR, 3145728);
        k_combine<true><<<12288, 256, 0, stream>>>(
            4, GpR, 3145728, 1536, QKVhR, nullptr, 0, nullptr, flag);
        k_transpose_bf<<<dim3(64, 16), 256, 0, stream>>>(QKVhR + 1024, 1536, 2048, 512, VtR);
        // flash attention (K-split z=4) + combine
        k_flash_row<<<dim3(32, 8, 4), 256, 0, stream>>>(QKVhR, VtR, GpR, MLp);
        k_flash_combine<<<4096, 256, 0, stream>>>(GpR, MLp, OhR);
        // ACC = OhR @ r_wo_w + r_wo_b + XN  (init + atomic split-K=4)
        k_castT<<<dim3(16, 64), 256, 0, stream>>>(r_wo_w, (size_t)d * 512 * 2048, 512, 2048, WtR, flag);
        k_combine<false><<<16384, 256, 0, stream>>>(
            0, nullptr, 0, 2048, ACC, r_wo_b, (size_t)d * DROW, XN, flag);
        k_mfma_at<2, 2><<<dim3(16, 16, 4), 256, 0, stream>>>(
            2048, 2048, 128, OhR, 512, WtR, 512, ACC);
        k_ln_row<<<BD, 256, 0, stream>>>(ACC, XN, XNh, r_ln2_g, r_ln2_b, (size_t)d * DROW, flag);
        // Hrow = XNh @ r_w1 + r_b1  (init + atomic split-K=4)
        k_castT<<<dim3(64, 64), 256, 0, stream>>>(r_w1, (size_t)d * 2048 * 2048, 2048, 2048, WtR, flag);
        k_combine<false><<<16384, 256, 0, stream>>>(
            0, nullptr, 0, 2048, Hrow, r_b1, (size_t)d * 2048, nullptr, flag);
        k_mfma_at<2, 2><<<dim3(16, 16, 4), 256, 0, stream>>>(
            2048, 2048, 512, XNh, 2048, WtR, 2048, Hrow);
        k_geglu_row<<<8192, 256, 0, stream>>>(Hrow, PmR);
        // X = PmR @ r_w2 + r_b2 + XN  (init + atomic split-K=4)
        k_castT<<<dim3(32, 64), 256, 0, stream>>>(r_w2, (size_t)d * 1024 * 2048, 1024, 2048, WtR, flag);
        k_combine<false><<<16384, 256, 0, stream>>>(
            0, nullptr, 0, 2048, X, r_b2, (size_t)d * DROW, XN, flag);
        k_mfma_at<2, 2><<<dim3(16, 16, 4), 256, 0, stream>>>(
            2048, 2048, 256, PmR, 1024, WtR, 1024, X);
    }

    k_cast_out<<<16384, 256, 0, stream>>>(X, d_out, flag);
}

// Round 3
// 2107.071 us; speedup vs baseline: 1.3344x; 1.3344x over previous
//
#include <hip/hip_runtime.h>
#include <hip/hip_bf16.h>
#include <cstddef>

#define BD    2048
#define NF    32
#define DIMC  64
#define HEADS 8
#define DROW  2048
#define LNEPS 1e-5f

typedef __hip_bfloat16 bf16;
typedef __attribute__((ext_vector_type(8))) short short8;
typedef __attribute__((ext_vector_type(4))) float f32x4;

#define MFMA16 __builtin_amdgcn_mfma_f32_16x16x32_bf16

__device__ inline float ldin(const void* p, size_t i, int bf) {
    if (bf) return __bfloat162float(((const bf16*)p)[i]);
    return ((const float*)p)[i];
}

__device__ inline float gelu_exact(float x) {
    return 0.5f * x * (1.0f + erff(x * 0.70710678118654752f));
}

// ---------------- dtype detector ----------------
__global__ __launch_bounds__(64) void k_detect(const void* __restrict__ x,
                                               int* __restrict__ flag) {
    int i = threadIdx.x;
    size_t idx = (size_t)(2 * i) * 16384;
    unsigned short u = ((const unsigned short*)x)[idx];
    int e = (u >> 7) & 0xFF;
    int plausible = (e == 0) || (e >= 96 && e <= 132);
    unsigned long long m = __ballot(plausible);
    if (i == 0) *flag = (__popcll(m) >= 48) ? 1 : 0;
}

// ---------------- concat ----------------
__global__ __launch_bounds__(256) void k_concat(const void* __restrict__ x,
                                                const void* __restrict__ xc,
                                                float* __restrict__ X,
                                                const int* __restrict__ flag) {
    const int bf = *flag;
    int i = blockIdx.x * 256 + threadIdx.x;
    int d = i & 63;
    int f = (i >> 6) & 31;
    int b = i >> 11;
    float v = (f < 16) ? ldin(x,  ((size_t)b * 16 + f) * 64 + d, bf)
                       : ldin(xc, ((size_t)b * 16 + (f - 16)) * 64 + d, bf);
    X[i] = v;
}

// ---------------- LayerNorm 64 (fp32 + bf16 out) ----------------
__global__ __launch_bounds__(256) void k_ln64(const float* __restrict__ in,
                                              float* __restrict__ out,
                                              bf16* __restrict__ outh,
                                              const void* __restrict__ g,
                                              const void* __restrict__ b,
                                              size_t eoff,
                                              const int* __restrict__ flag) {
    const int bf = *flag;
    int row  = blockIdx.x * 4 + (threadIdx.x >> 6);
    int lane = threadIdx.x & 63;
    float v = in[(size_t)row * 64 + lane];
    float s = v;
    #pragma unroll
    for (int off = 32; off; off >>= 1) s += __shfl_xor(s, off);
    float mean = s * (1.0f / 64.0f);
    float dx = v - mean;
    float s2 = dx * dx;
    #pragma unroll
    for (int off = 32; off; off >>= 1) s2 += __shfl_xor(s2, off);
    float inv = rsqrtf(s2 * (1.0f / 64.0f) + LNEPS);
    float o = dx * inv * ldin(g, eoff + lane, bf) + ldin(b, eoff + lane, bf);
    out[(size_t)row * 64 + lane]  = o;
    outh[(size_t)row * 64 + lane] = __float2bfloat16(o);
}

// ---------------- LayerNorm 2048 (fp32 + bf16 out) ----------------
__global__ __launch_bounds__(256) void k_ln_row(const float* __restrict__ in,
                                                float* __restrict__ out,
                                                bf16* __restrict__ outh,
                                                const void* __restrict__ g,
                                                const void* __restrict__ b,
                                                size_t eoff,
                                                const int* __restrict__ flag) {
    const int bf = *flag;
    const int row = blockIdx.x, tid = threadIdx.x;
    __shared__ float red[4];
    const float* r = in + (size_t)row * DROW;
    float v[8];
    float s = 0.f;
    #pragma unroll
    for (int i = 0; i < 8; ++i) { v[i] = r[tid + i * 256]; s += v[i]; }
    #pragma unroll
    for (int off = 32; off; off >>= 1) s += __shfl_xor(s, off);
    if ((tid & 63) == 0) red[tid >> 6] = s;
    __syncthreads();
    float mean = (red[0] + red[1] + red[2] + red[3]) * (1.0f / DROW);
    __syncthreads();
    float s2 = 0.f;
    #pragma unroll
    for (int i = 0; i < 8; ++i) { float dx = v[i] - mean; s2 += dx * dx; }
    #pragma unroll
    for (int off = 32; off; off >>= 1) s2 += __shfl_xor(s2, off);
    if ((tid & 63) == 0) red[tid >> 6] = s2;
    __syncthreads();
    float inv = rsqrtf((red[0] + red[1] + red[2] + red[3]) * (1.0f / DROW) + LNEPS);
    #pragma unroll
    for (int i = 0; i < 8; ++i) {
        int j = tid + i * 256;
        float o = (v[i] - mean) * inv * ldin(g, eoff + j, bf) + ldin(b, eoff + j, bf);
        out[(size_t)row * DROW + j]  = o;
        outh[(size_t)row * DROW + j] = __float2bfloat16(o);
    }
}

// ---------------- transpose+cast weight ----------------
__global__ __launch_bounds__(256) void k_castT(const void* __restrict__ in, size_t eoff,
                                               int R, int C,
                                               bf16* __restrict__ out,
                                               const int* __restrict__ flag) {
    const int bf = *flag;
    __shared__ bf16 tile[32][33];
    const int tx = threadIdx.x & 31, ty = threadIdx.x >> 5;
    const int bx = blockIdx.x, by = blockIdx.y;
    #pragma unroll
    for (int k = 0; k < 4; ++k) {
        int r = bx * 32 + ty + k * 8;
        int c = by * 32 + tx;
        tile[ty + k * 8][tx] = __float2bfloat16(ldin(in, eoff + (size_t)r * C + c, bf));
    }
    __syncthreads();
    #pragma unroll
    for (int k = 0; k < 4; ++k) {
        int oc = by * 32 + ty + k * 8;
        int orr = bx * 32 + tx;
        out[(size_t)oc * R + orr] = tile[tx][ty + k * 8];
    }
}

// ---------------- transpose bf16 ----------------
__global__ __launch_bounds__(256) void k_transpose_bf(const bf16* __restrict__ in, int ld,
                                                      int R, int C,
                                                      bf16* __restrict__ out) {
    __shared__ bf16 tile[32][33];
    const int tx = threadIdx.x & 31, ty = threadIdx.x >> 5;
    const int bx = blockIdx.x, by = blockIdx.y;
    #pragma unroll
    for (int k = 0; k < 4; ++k) {
        int r = bx * 32 + ty + k * 8;
        int c = by * 32 + tx;
        tile[ty + k * 8][tx] = in[(size_t)r * ld + c];
    }
    __syncthreads();
    #pragma unroll
    for (int k = 0; k < 4; ++k) {
        int oc = by * 32 + ty + k * 8;
        int orr = bx * 32 + tx;
        out[(size_t)oc * R + orr] = tile[tx][ty + k * 8];
    }
}

// ---------------- MFMA GEMM split-K: z = K-chunk, fp32 partials ----------------
template <int WM, int WN>
__global__ __launch_bounds__(256) void k_mfma_sk(
    int M, int N, int KC,
    const bf16* __restrict__ A, int lda,
    const bf16* __restrict__ Bt, int ldb,
    float* __restrict__ Cp, long long pstride)
{
    constexpr int TM = WM * 64, TN = WN * 64;
    const int z = blockIdx.z;
    const int m0 = blockIdx.y * TM, n0 = blockIdx.x * TN;
    const int tid = threadIdx.x, lane = tid & 63, wave = tid >> 6;
    const int wy = wave / WN, wx = wave % WN;
    __shared__ short As[TM][72];
    __shared__ short Bs[TN][72];
    f32x4 acc[4][4] = {};
    const int row8 = tid >> 3, chunk = (tid & 7) * 8;
    const int kend = z * KC + KC;
    for (int k0 = z * KC; k0 < kend; k0 += 64) {
        #pragma unroll
        for (int i = 0; i < TM / 32; ++i) {
            int r = i * 32 + row8;
            *(short8*)&As[r][chunk] =
                *(const short8*)(A + (size_t)(m0 + r) * lda + k0 + chunk);
        }
        #pragma unroll
        for (int i = 0; i < TN / 32; ++i) {
            int r = i * 32 + row8;
            *(short8*)&Bs[r][chunk] =
                *(const short8*)(Bt + (size_t)(n0 + r) * ldb + k0 + chunk);
        }
        __syncthreads();
        #pragma unroll
        for (int ks = 0; ks < 64; ks += 32) {
            short8 af[4], bfr[4];
            #pragma unroll
            for (int mt = 0; mt < 4; ++mt)
                af[mt] = *(const short8*)&As[wy * 64 + mt * 16 + (lane & 15)][ks + (lane >> 4) * 8];
            #pragma unroll
            for (int nt = 0; nt < 4; ++nt)
                bfr[nt] = *(const short8*)&Bs[wx * 64 + nt * 16 + (lane & 15)][ks + (lane >> 4) * 8];
            #pragma unroll
            for (int mt = 0; mt < 4; ++mt)
                #pragma unroll
                for (int nt = 0; nt < 4; ++nt)
                    acc[mt][nt] = MFMA16(af[mt], bfr[nt], acc[mt][nt], 0, 0, 0);
        }
        __syncthreads();
    }
    float* Co = Cp + (size_t)z * pstride;
    #pragma unroll
    for (int mt = 0; mt < 4; ++mt)
        #pragma unroll
        for (int r = 0; r < 4; ++r) {
            int m = m0 + wy * 64 + mt * 16 + (lane >> 4) * 4 + r;
            #pragma unroll
            for (int nt = 0; nt < 4; ++nt) {
                int n = n0 + wx * 64 + nt * 16 + (lane & 15);
                Co[(size_t)m * N + n] = acc[mt][nt][r];
            }
        }
}

// ---------------- split-K combine: out = sum partials (+bias)(+addend) ----------------
template <bool OBF>
__global__ __launch_bounds__(256) void k_combine(
    int KS, const float* __restrict__ P, long long pstride, int N,
    void* __restrict__ C,
    const void* __restrict__ bias, size_t biasOff,
    const float* __restrict__ addend,
    const int* __restrict__ flag)
{
    int i = blockIdx.x * 256 + threadIdx.x;
    float v = 0.f;
    for (int z = 0; z < KS; ++z) v += P[(size_t)z * pstride + i];
    if (bias)   v += ldin(bias, biasOff + (size_t)(i % N), bias ? *flag : 0);
    if (addend) v += addend[i];
    if constexpr (OBF) ((bf16*)C)[i] = __float2bfloat16(v);
    else               ((float*)C)[i] = v;
}

// ---------------- QKV projection sub-tile: c += X(32x64) @ W_h(64x64) ----------------
__device__ inline void proj_tile(const short8 xa[2][2], const bf16* __restrict__ wbase,
                                 int l15, int quad, f32x4 c[2][4]) {
    #pragma unroll
    for (int nt = 0; nt < 4; ++nt) {
        short8 b0 = *(const short8*)(wbase + (size_t)(nt * 16 + l15) * 64 + quad * 8);
        short8 b1 = *(const short8*)(wbase + (size_t)(nt * 16 + l15) * 64 + 32 + quad * 8);
        #pragma unroll
        for (int mt = 0; mt < 2; ++mt) {
            c[mt][nt] = MFMA16(xa[mt][0], b0, c[mt][nt], 0, 0, 0);
            c[mt][nt] = MFMA16(xa[mt][1], b1, c[mt][nt], 0, 0, 0);
        }
    }
}

// ---------------- fused col QKV-proj + attention (per-wave LDS, 2-buffer, no barriers) ----------------
// Softmax: logits bounded -> no-max softmax, unnormalized P; O scaled by 1/rowsum.
__global__ __launch_bounds__(256) void k_col_qkv_attn(
    const bf16* __restrict__ Xh, const bf16* __restrict__ Wt,
    bf16* __restrict__ Oh)
{
    __shared__ __align__(16) short bufA[4][2304];   // Q (32x72) -> P
    __shared__ __align__(16) short bufB[4][2304];   // K (32x72) -> V^T (64x36)
    const int tid = threadIdx.x, lane = tid & 63, wave = tid >> 6;
    const int task = blockIdx.x * 4 + wave;   // sample*8 + head
    const int s = task >> 3, h = task & 7;
    const int l15 = lane & 15, quad = lane >> 4;
    short* A  = bufA[wave];
    short* Bb = bufB[wave];

    short8 xa[2][2];
    #pragma unroll
    for (int mt = 0; mt < 2; ++mt)
        #pragma unroll
        for (int kc = 0; kc < 2; ++kc)
            xa[mt][kc] = *(const short8*)(Xh + (size_t)(s * 32 + mt * 16 + l15) * 64 + kc * 32 + quad * 8);

    // ---- Q -> A (C-layout, stride 72) ----
    {
        f32x4 c[2][4] = {};
        proj_tile(xa, Wt + (size_t)(h * 64) * 64, l15, quad, c);
        #pragma unroll
        for (int mt = 0; mt < 2; ++mt)
            #pragma unroll
            for (int nt = 0; nt < 4; ++nt)
                #pragma unroll
                for (int r = 0; r < 4; ++r)
                    *(bf16*)&A[(mt * 16 + quad * 4 + r) * 72 + nt * 16 + l15] =
                        __float2bfloat16(c[mt][nt][r]);
    }
    // ---- K -> Bb (C-layout, stride 72) ----
    {
        f32x4 c[2][4] = {};
        proj_tile(xa, Wt + (size_t)(512 + h * 64) * 64, l15, quad, c);
        #pragma unroll
        for (int mt = 0; mt < 2; ++mt)
            #pragma unroll
            for (int nt = 0; nt < 4; ++nt)
                #pragma unroll
                for (int r = 0; r < 4; ++r)
                    *(bf16*)&Bb[(mt * 16 + quad * 4 + r) * 72 + nt * 16 + l15] =
                        __float2bfloat16(c[mt][nt][r]);
    }
    // ---- S = Q @ K^T ----
    f32x4 S[2][2] = {};
    #pragma unroll
    for (int mt = 0; mt < 2; ++mt) {
        short8 qa0 = *(const short8*)&A[(mt * 16 + l15) * 72 + quad * 8];
        short8 qa1 = *(const short8*)&A[(mt * 16 + l15) * 72 + 32 + quad * 8];
        #pragma unroll
        for (int nt = 0; nt < 2; ++nt) {
            short8 kb0 = *(const short8*)&Bb[(nt * 16 + l15) * 72 + quad * 8];
            short8 kb1 = *(const short8*)&Bb[(nt * 16 + l15) * 72 + 32 + quad * 8];
            S[mt][nt] = MFMA16(qa0, kb0, S[mt][nt], 0, 0, 0);
            S[mt][nt] = MFMA16(qa1, kb1, S[mt][nt], 0, 0, 0);
        }
    }
    // ---- V -> Bb transposed ([64][36]; K dead after S) ----
    {
        f32x4 c[2][4] = {};
        proj_tile(xa, Wt + (size_t)(1024 + h * 64) * 64, l15, quad, c);
        #pragma unroll
        for (int mt = 0; mt < 2; ++mt)
            #pragma unroll
            for (int nt = 0; nt < 4; ++nt)
                #pragma unroll
                for (int r = 0; r < 4; ++r)
                    *(bf16*)&Bb[(nt * 16 + l15) * 36 + mt * 16 + quad * 4 + r] =
                        __float2bfloat16(c[mt][nt][r]);
    }
    // ---- no-max softmax; unnormalized P -> A (Q dead); keep 1/rowsum ----
    float inv[2][4];
    #pragma unroll
    for (int mt = 0; mt < 2; ++mt) {
        #pragma unroll
        for (int ri = 0; ri < 4; ++ri) {
            float e0 = __expf(S[mt][0][ri] * 0.125f);
            float e1 = __expf(S[mt][1][ri] * 0.125f);
            float sum = e0 + e1;
            #pragma unroll
            for (int msk = 1; msk < 16; msk <<= 1) sum += __shfl_xor(sum, msk);
            inv[mt][ri] = 1.0f / sum;
            int row = mt * 16 + quad * 4 + ri;
            *(bf16*)&A[row * 72 + l15]      = __float2bfloat16(e0);
            *(bf16*)&A[row * 72 + 16 + l15] = __float2bfloat16(e1);
        }
    }
    // ---- O = P @ V, then normalize ----
    short8 pa[2];
    #pragma unroll
    for (int mt = 0; mt < 2; ++mt)
        pa[mt] = *(const short8*)&A[(mt * 16 + l15) * 72 + quad * 8];
    f32x4 O[2][4] = {};
    #pragma unroll
    for (int nt = 0; nt < 4; ++nt) {
        short8 vb = *(const short8*)&Bb[(nt * 16 + l15) * 36 + quad * 8];
        #pragma unroll
        for (int mt = 0; mt < 2; ++mt)
            O[mt][nt] = MFMA16(pa[mt], vb, O[mt][nt], 0, 0, 0);
    }
    #pragma unroll
    for (int mt = 0; mt < 2; ++mt)
        #pragma unroll
        for (int nt = 0; nt < 4; ++nt)
            #pragma unroll
            for (int ri = 0; ri < 4; ++ri) {
                size_t row = (size_t)s * 32 + mt * 16 + quad * 4 + ri;
                Oh[row * 512 + h * 64 + nt * 16 + l15] =
                    __float2bfloat16(O[mt][nt][ri] * inv[mt][ri]);
            }
}

// ---------------- fused col wo-proj + bias + residual ----------------
// ACC[65536x64] = Oh[65536x512] @ wo(512x64) + wo_b + XN.  N=64 -> single N-tile,
// so A is read exactly once; per-wave 32 rows, K=512 swept in registers, B-frags
// straight from L2 (WcO [64][512]), no LDS, no partials, no combine.
__global__ __launch_bounds__(256) void k_col_wo(
    const bf16* __restrict__ Oh, const bf16* __restrict__ Wt,
    const void* __restrict__ bias, size_t biasOff,
    const float* __restrict__ XN, float* __restrict__ ACC,
    const int* __restrict__ flag)
{
    const int lane = threadIdx.x & 63, wave = threadIdx.x >> 6;
    const int rb = (blockIdx.x * 4 + wave) * 32;
    const int l15 = lane & 15, quad = lane >> 4;
    f32x4 acc[2][4] = {};
    #pragma unroll 2
    for (int kc = 0; kc < 512; kc += 32) {
        short8 a0 = *(const short8*)(Oh + (size_t)(rb + l15) * 512 + kc + quad * 8);
        short8 a1 = *(const short8*)(Oh + (size_t)(rb + 16 + l15) * 512 + kc + quad * 8);
        #pragma unroll
        for (int nt = 0; nt < 4; ++nt) {
            short8 b = *(const short8*)(Wt + (size_t)(nt * 16 + l15) * 512 + kc + quad * 8);
            acc[0][nt] = MFMA16(a0, b, acc[0][nt], 0, 0, 0);
            acc[1][nt] = MFMA16(a1, b, acc[1][nt], 0, 0, 0);
        }
    }
    const int bf = *flag;
    #pragma unroll
    for (int nt = 0; nt < 4; ++nt) {
        float bv = ldin(bias, biasOff + nt * 16 + l15, bf);
        #pragma unroll
        for (int mt = 0; mt < 2; ++mt)
            #pragma unroll
            for (int r = 0; r < 4; ++r) {
                size_t idx = (size_t)(rb + mt * 16 + quad * 4 + r) * 64 + nt * 16 + l15;
                ACC[idx] = acc[mt][nt][r] + bv + XN[idx];
            }
    }
}

// ---------------- fused col GEGLU MLP ----------------
// X[65536x64] = geglu(XNh @ w1 + b1) @ w2 + b2 + XN, all in one kernel.
// Per-wave 32 rows. For each 64-col chunk jc: compute H_a (cols jc..jc+64) and
// H_g (cols 256+jc..) as MFMA accs, bias+gelu in fp32, P -> per-wave LDS (32x72)
// to reshape C-layout -> A-frag, then accumulate P_chunk @ w2[jc:jc+64,:].
// H stays fp32 (more accurate than prior bf16 H1); P bf16 as before.
__global__ __launch_bounds__(256) void k_col_mlp(
    const bf16* __restrict__ Xh,   // [65536][64] ln2 bf16
    const bf16* __restrict__ W1t,  // [512][64]
    const bf16* __restrict__ W2t,  // [64][256]
    const void* __restrict__ b1, size_t b1Off,
    const void* __restrict__ b2, size_t b2Off,
    const float* __restrict__ XN, float* __restrict__ Xout,
    const int* __restrict__ flag)
{
    __shared__ __align__(16) short Pl[4][32][72];
    const int lane = threadIdx.x & 63, wave = threadIdx.x >> 6;
    const int rb = (blockIdx.x * 4 + wave) * 32;
    const int l15 = lane & 15, quad = lane >> 4;
    const int bf = *flag;
    short (*P)[72] = Pl[wave];

    short8 xa[2][2];
    #pragma unroll
    for (int mt = 0; mt < 2; ++mt)
        #pragma unroll
        for (int kc = 0; kc < 2; ++kc)
            xa[mt][kc] = *(const short8*)(Xh + (size_t)(rb + mt * 16 + l15) * 64 + kc * 32 + quad * 8);

    f32x4 xacc[2][4] = {};
    #pragma unroll
    for (int jc = 0; jc < 256; jc += 64) {
        // H_a, H_g chunks (32x64 each)
        f32x4 ca[2][4] = {}, cg[2][4] = {};
        #pragma unroll
        for (int nt = 0; nt < 4; ++nt) {
            const bf16* wa = W1t + (size_t)(jc + nt * 16 + l15) * 64;
            short8 a0 = *(const short8*)(wa + quad * 8);
            short8 a1 = *(const short8*)(wa + 32 + quad * 8);
            const bf16* wg = W1t + (size_t)(256 + jc + nt * 16 + l15) * 64;
            short8 g0 = *(const short8*)(wg + quad * 8);
            short8 g1 = *(const short8*)(wg + 32 + quad * 8);
            #pragma unroll
            for (int mt = 0; mt < 2; ++mt) {
                ca[mt][nt] = MFMA16(xa[mt][0], a0, ca[mt][nt], 0, 0, 0);
                ca[mt][nt] = MFMA16(xa[mt][1], a1, ca[mt][nt], 0, 0, 0);
                cg[mt][nt] = MFMA16(xa[mt][0], g0, cg[mt][nt], 0, 0, 0);
                cg[mt][nt] = MFMA16(xa[mt][1], g1, cg[mt][nt], 0, 0, 0);
            }
        }
        // bias + geglu -> P (per-wave LDS; in-order DS pipe, no barrier)
        #pragma unroll
        for (int nt = 0; nt < 4; ++nt) {
            float ba = ldin(b1, b1Off + jc + nt * 16 + l15, bf);
            float bg = ldin(b1, b1Off + 256 + jc + nt * 16 + l15, bf);
            #pragma unroll
            for (int mt = 0; mt < 2; ++mt)
                #pragma unroll
                for (int r = 0; r < 4; ++r) {
                    float p = (ca[mt][nt][r] + ba) * gelu_exact(cg[mt][nt][r] + bg);
                    *(bf16*)&P[mt * 16 + quad * 4 + r][nt * 16 + l15] = __float2bfloat16(p);
                }
        }
        // xacc += P_chunk(32x64) @ w2[jc:jc+64, :64]
        short8 p0[2], p1[2];
        #pragma unroll
        for (int mt = 0; mt < 2; ++mt) {
            p0[mt] = *(const short8*)&P[mt * 16 + l15][quad * 8];
            p1[mt] = *(const short8*)&P[mt * 16 + l15][32 + quad * 8];
        }
        #pragma unroll
        for (int nt = 0; nt < 4; ++nt) {
            short8 w0 = *(const short8*)(W2t + (size_t)(nt * 16 + l15) * 256 + jc + quad * 8);
            short8 w1 = *(const short8*)(W2t + (size_t)(nt * 16 + l15) * 256 + jc + 32 + quad * 8);
            #pragma unroll
            for (int mt = 0; mt < 2; ++mt) {
                xacc[mt][nt] = MFMA16(p0[mt], w0, xacc[mt][nt], 0, 0, 0);
                xacc[mt][nt] = MFMA16(p1[mt], w1, xacc[mt][nt], 0, 0, 0);
            }
        }
    }
    #pragma unroll
    for (int nt = 0; nt < 4; ++nt) {
        float bv = ldin(b2, b2Off + nt * 16 + l15, bf);
        #pragma unroll
        for (int mt = 0; mt < 2; ++mt)
            #pragma unroll
            for (int r = 0; r < 4; ++r) {
                size_t idx = (size_t)(rb + mt * 16 + quad * 4 + r) * 64 + nt * 16 + l15;
                Xout[idx] = xacc[mt][nt][r] + bv + XN[idx];
            }
    }
}

// ---------------- flash row attention v2: K-split, barrier-free ----------------
__global__ __launch_bounds__(256) void k_flash_row(
    const bf16* __restrict__ QKV, const bf16* __restrict__ Vt,
    float* __restrict__ Opart, float* __restrict__ ML)
{
    __shared__ __align__(16) short Ps[4][16][136];
    const int tid = threadIdx.x, lane = tid & 63, wave = tid >> 6;
    const int h = blockIdx.y, z = blockIdx.z;
    const int q0 = blockIdx.x * 64 + wave * 16;
    const int l15 = lane & 15, quad = lane >> 4;

    short8 qa[2];
    #pragma unroll
    for (int kc = 0; kc < 2; ++kc)
        qa[kc] = *(const short8*)(QKV + (size_t)(q0 + l15) * 1536 + h * 64 + kc * 32 + quad * 8);

    float mi[4], li[4];
    #pragma unroll
    for (int r = 0; r < 4; ++r) { mi[r] = -1e30f; li[r] = 0.f; }
    f32x4 Oa[4] = {};

    #pragma unroll
    for (int jj = 0; jj < 4; ++jj) {
        const int j = z * 4 + jj;
        f32x4 s[8] = {};
        #pragma unroll
        for (int nt = 0; nt < 8; ++nt) {
            const bf16* krow = QKV + (size_t)(j * 128 + nt * 16 + l15) * 1536 + 512 + h * 64;
            short8 kb0 = *(const short8*)(krow + quad * 8);
            short8 kb1 = *(const short8*)(krow + 32 + quad * 8);
            s[nt] = MFMA16(qa[0], kb0, s[nt], 0, 0, 0);
            s[nt] = MFMA16(qa[1], kb1, s[nt], 0, 0, 0);
        }
        #pragma unroll
        for (int r = 0; r < 4; ++r) {
            float mt = -1e30f;
            #pragma unroll
            for (int nt = 0; nt < 8; ++nt) { s[nt][r] *= 0.125f; mt = fmaxf(mt, s[nt][r]); }
            #pragma unroll
            for (int msk = 1; msk < 16; msk <<= 1) mt = fmaxf(mt, __shfl_xor(mt, msk));
            float mn = fmaxf(mi[r], mt);
            float alpha = __expf(mi[r] - mn);
            float ls = 0.f;
            #pragma unroll
            for (int nt = 0; nt < 8; ++nt) { float p = __expf(s[nt][r] - mn); s[nt][r] = p; ls += p; }
            #pragma unroll
            for (int msk = 1; msk < 16; msk <<= 1) ls += __shfl_xor(ls, msk);
            li[r] = li[r] * alpha + ls;
            mi[r] = mn;
            #pragma unroll
            for (int nt = 0; nt < 4; ++nt) Oa[nt][r] *= alpha;
            int row = quad * 4 + r;
            #pragma unroll
            for (int nt = 0; nt < 8; ++nt)
                *(bf16*)&Ps[wave][row][nt * 16 + l15] = __float2bfloat16(s[nt][r]);
        }
        short8 pa[4];
        #pragma unroll
        for (int kc = 0; kc < 4; ++kc)
            pa[kc] = *(const short8*)&Ps[wave][l15][kc * 32 + quad * 8];
        #pragma unroll
        for (int nt = 0; nt < 4; ++nt) {
            #pragma unroll
            for (int kc = 0; kc < 4; ++kc) {
                short8 vb = *(const short8*)(Vt + (size_t)(h * 64 + nt * 16 + l15) * 2048 +
                                             j * 128 + kc * 32 + quad * 8);
                Oa[nt] = MFMA16(pa[kc], vb, Oa[nt], 0, 0, 0);
            }
        }
    }
    float* Op = Opart + (size_t)z * 1048576;
    #pragma unroll
    for (int nt = 0; nt < 4; ++nt)
        #pragma unroll
        for (int r = 0; r < 4; ++r)
            Op[(size_t)(q0 + quad * 4 + r) * 512 + h * 64 + nt * 16 + l15] = Oa[nt][r];
    if (l15 == 0) {
        #pragma unroll
        for (int r = 0; r < 4; ++r) {
            int row = q0 + quad * 4 + r;
            ML[((size_t)(z * 8 + h) * 2048 + row) * 2]     = mi[r];
            ML[((size_t)(z * 8 + h) * 2048 + row) * 2 + 1] = li[r];
        }
    }
}

// ---------------- flash combine ----------------
__global__ __launch_bounds__(256) void k_flash_combine(
    const float* __restrict__ Opart, const float* __restrict__ ML,
    bf16* __restrict__ O)
{
    int i = blockIdx.x * 256 + threadIdx.x;     // 2048*512
    int row = i >> 9, n = i & 511, h = n >> 6;
    float m[4], l[4], M = -1e30f;
    #pragma unroll
    for (int z = 0; z < 4; ++z) {
        m[z] = ML[((size_t)(z * 8 + h) * 2048 + row) * 2];
        l[z] = ML[((size_t)(z * 8 + h) * 2048 + row) * 2 + 1];
        M = fmaxf(M, m[z]);
    }
    float num = 0.f, den = 0.f;
    #pragma unroll
    for (int z = 0; z < 4; ++z) {
        float w = __expf(m[z] - M);
        num += w * Opart[(size_t)z * 1048576 + i];
        den += w * l[z];
    }
    O[i] = __float2bfloat16(num / den);
}

// ---------------- GEGLU row ----------------
__global__ __launch_bounds__(256) void k_geglu_row(const float* __restrict__ H,
                                                   bf16* __restrict__ P) {
    int i = blockIdx.x * 256 + threadIdx.x;
    int r = i >> 10, j = i & 1023;
    float a = H[(size_t)r * 2048 + j];
    float g = H[(size_t)r * 2048 + 1024 + j];
    P[i] = __float2bfloat16(a * gelu_exact(g));
}

// ---------------- final cast ----------------
__global__ __launch_bounds__(256) void k_cast_out(const float* __restrict__ X,
                                                  void* __restrict__ out,
                                                  const int* __restrict__ flag) {
    const int bf = *flag;
    int i = blockIdx.x * 256 + threadIdx.x;
    if (bf) ((bf16*)out)[i] = __float2bfloat16(X[i]);
    else    ((float*)out)[i] = X[i];
}

// =====================================================================
extern "C" void kernel_launch(void* const* d_in, const int* in_sizes, int n_in,
                              void* d_out, int out_size, void* d_ws, size_t ws_size,
                              hipStream_t stream) {
    const void* x       = d_in[0];
    const void* x_cont  = d_in[1];
    const void* c_ln1_g = d_in[2];
    const void* c_ln1_b = d_in[3];
    const void* c_wqkv  = d_in[4];
    const void* c_wo_w  = d_in[5];
    const void* c_wo_b  = d_in[6];
    const void* c_ln2_g = d_in[7];
    const void* c_ln2_b = d_in[8];
    const void* c_w1    = d_in[9];
    const void* c_b1    = d_in[10];
    const void* c_w2    = d_in[11];
    const void* c_b2    = d_in[12];
    const void* r_ln1_g = d_in[13];
    const void* r_ln1_b = d_in[14];
    const void* r_wqkv  = d_in[15];
    const void* r_wo_w  = d_in[16];
    const void* r_wo_b  = d_in[17];
    const void* r_ln2_g = d_in[18];
    const void* r_ln2_b = d_in[19];
    const void* r_w1    = d_in[20];
    const void* r_b1    = d_in[21];
    const void* r_w2    = d_in[22];
    const void* r_b2    = d_in[23];

    const size_t NX = (size_t)BD * NF * DIMC;        // 4,194,304
    float* X   = (float*)d_ws;
    float* XN  = X   + NX;
    float* ACC = XN  + NX;
    bf16* XNh  = (bf16*)(ACC + NX);
    bf16* WtR  = XNh + NX;                            // <=2048x2048
    bf16* WcQ  = WtR + (size_t)2048 * 2048;           // 1536x64
    bf16* WcO  = WcQ + 98304;                         // 64x512
    bf16* Wc1  = WcO + 32768;                         // 512x64
    bf16* Wc2  = Wc1 + 32768;                         // 64x256
    bf16* Sc   = Wc2 + 16384;                         // scratch union base

    // col block overlays:
    bf16*  OhC  = Sc;                                         // [0, 64 MiB)
    // row block overlays:
    bf16*  QKVhR = Sc;                                        // 6.3MB
    bf16*  VtR   = QKVhR + 3145728;                           // 2.1MB
    bf16*  OhR   = VtR + 1048576;                             // 2.1MB
    bf16*  PmR   = OhR + 1048576;                             // 4.2MB
    float* Hrow  = (float*)(PmR + 2097152);                   // 16.8MB (ends 31.5MB)
    float* GpR   = (float*)((char*)Sc + 33554432);            // row partials (ends 96 MiB)
    float* MLp   = GpR + (size_t)4 * 1048576;                 // flash m/l (1MB)

    char* scEnd = (char*)Sc + 100663296;                      // 96 MiB
    int*  flag  = (int*)scEnd;
    const size_t need = (size_t)(scEnd + 64 - (char*)d_ws);
    if (ws_size < need) return;

    k_detect<<<1, 64, 0, stream>>>(x, flag);
    k_concat<<<16384, 256, 0, stream>>>(x, x_cont, X, flag);

    for (int d = 0; d < 4; ++d) {
        // ================= col block =================
        k_ln64<<<16384, 256, 0, stream>>>(X, XN, XNh, c_ln1_g, c_ln1_b, (size_t)d * 64, flag);
        k_castT<<<dim3(2, 48), 256, 0, stream>>>(c_wqkv, (size_t)d * 64 * 1536, 64, 1536, WcQ, flag);
        k_col_qkv_attn<<<4096, 256, 0, stream>>>(XNh, WcQ, OhC);
        // ACC = OhC @ c_wo_w + c_wo_b + XN  (fused, no partials)
        k_castT<<<dim3(16, 2), 256, 0, stream>>>(c_wo_w, (size_t)d * 512 * 64, 512, 64, WcO, flag);
        k_col_wo<<<512, 256, 0, stream>>>(OhC, WcO, c_wo_b, (size_t)d * 64, XN, ACC, flag);
        k_ln64<<<16384, 256, 0, stream>>>(ACC, XN, XNh, c_ln2_g, c_ln2_b, (size_t)d * 64, flag);
        // X = geglu(XNh @ c_w1 + c_b1) @ c_w2 + c_b2 + XN  (fully fused MLP)
        k_castT<<<dim3(2, 16), 256, 0, stream>>>(c_w1, (size_t)d * 64 * 512, 64, 512, Wc1, flag);
        k_castT<<<dim3(8, 2), 256, 0, stream>>>(c_w2, (size_t)d * 256 * 64, 256, 64, Wc2, flag);
        k_col_mlp<<<512, 256, 0, stream>>>(XNh, Wc1, Wc2,
                                           c_b1, (size_t)d * 512, c_b2, (size_t)d * 64,
                                           XN, X, flag);

        // ================= row block =================
        k_ln_row<<<BD, 256, 0, stream>>>(X, XN, XNh, r_ln1_g, r_ln1_b, (size_t)d * DROW, flag);
        // QKVhR = XNh @ r_wqkv  (split-K=4)
        k_castT<<<dim3(64, 48), 256, 0, stream>>>(r_wqkv, (size_t)d * 2048 * 1536, 2048, 1536, WtR, flag);
        k_mfma_sk<2, 2><<<dim3(12, 16, 4), 256, 0, stream>>>(
            2048, 1536, 512, XNh, 2048, WtR, 2048, GpR, 3145728);
        k_combine<true><<<12288, 256, 0, stream>>>(
            4, GpR, 3145728, 1536, QKVhR, nullptr, 0, nullptr, flag);
        k_transpose_bf<<<dim3(64, 16), 256, 0, stream>>>(QKVhR + 1024, 1536, 2048, 512, VtR);
        // flash attention (K-split z=4) + combine
        k_flash_row<<<dim3(32, 8, 4), 256, 0, stream>>>(QKVhR, VtR, GpR, MLp);
        k_flash_combine<<<4096, 256, 0, stream>>>(GpR, MLp, OhR);
        // ACC = OhR @ r_wo_w + r_wo_b + XN  (split-K=4)
        k_castT<<<dim3(16, 64), 256, 0, stream>>>(r_wo_w, (size_t)d * 512 * 2048, 512, 2048, WtR, flag);
        k_mfma_sk<2, 2><<<dim3(16, 16, 4), 256, 0, stream>>>(
            2048, 2048, 128, OhR, 512, WtR, 512, GpR, 4194304);
        k_combine<false><<<16384, 256, 0, stream>>>(
            4, GpR, 4194304, 2048, ACC, r_wo_b, (size_t)d * DROW, XN, flag);
        k_ln_row<<<BD, 256, 0, stream>>>(ACC, XN, XNh, r_ln2_g, r_ln2_b, (size_t)d * DROW, flag);
        // Hrow = XNh @ r_w1 + r_b1  (split-K=4)
        k_castT<<<dim3(64, 64), 256, 0, stream>>>(r_w1, (size_t)d * 2048 * 2048, 2048, 2048, WtR, flag);
        k_mfma_sk<2, 2><<<dim3(16, 16, 4), 256, 0, stream>>>(
            2048, 2048, 512, XNh, 2048, WtR, 2048, GpR, 4194304);
        k_combine<false><<<16384, 256, 0, stream>>>(
            4, GpR, 4194304, 2048, Hrow, r_b1, (size_t)d * 2048, nullptr, flag);
        k_geglu_row<<<8192, 256, 0, stream>>>(Hrow, PmR);
        // X = PmR @ r_w2 + r_b2 + XN  (split-K=4)
        k_castT<<<dim3(32, 64), 256, 0, stream>>>(r_w2, (size_t)d * 1024 * 2048, 1024, 2048, WtR, flag);
        k_mfma_sk<2, 2><<<dim3(16, 16, 4), 256, 0, stream>>>(
            2048, 2048, 256, PmR, 1024, WtR, 1024, GpR, 4194304);
        k_combine<false><<<16384, 256, 0, stream>>>(
            4, GpR, 4194304, 2048, X, r_b2, (size_t)d * DROW, XN, flag);
    }

    k_cast_out<<<16384, 256, 0, stream>>>(X, d_out, flag);
}

// Round 5
// 1923.571 us; speedup vs baseline: 1.4617x; 1.0954x over previous
//
#include <hip/hip_runtime.h>
#include <hip/hip_bf16.h>
#include <cstddef>

#define BD    2048
#define NF    32
#define DIMC  64
#define HEADS 8
#define DROW  2048
#define LNEPS 1e-5f

typedef __hip_bfloat16 bf16;
typedef __attribute__((ext_vector_type(8))) short short8;
typedef __attribute__((ext_vector_type(4))) float f32x4;

#define MFMA16 __builtin_amdgcn_mfma_f32_16x16x32_bf16

__device__ inline float ldin(const void* p, size_t i, int bf) {
    if (bf) return __bfloat162float(((const bf16*)p)[i]);
    return ((const float*)p)[i];
}

__device__ inline float gelu_exact(float x) {
    return 0.5f * x * (1.0f + erff(x * 0.70710678118654752f));
}

// ---------------- dtype detector ----------------
__global__ __launch_bounds__(64) void k_detect(const void* __restrict__ x,
                                               int* __restrict__ flag) {
    int i = threadIdx.x;
    size_t idx = (size_t)(2 * i) * 16384;
    unsigned short u = ((const unsigned short*)x)[idx];
    int e = (u >> 7) & 0xFF;
    int plausible = (e == 0) || (e >= 96 && e <= 132);
    unsigned long long m = __ballot(plausible);
    if (i == 0) *flag = (__popcll(m) >= 48) ? 1 : 0;
}

// ---------------- concat ----------------
__global__ __launch_bounds__(256) void k_concat(const void* __restrict__ x,
                                                const void* __restrict__ xc,
                                                float* __restrict__ X,
                                                const int* __restrict__ flag) {
    const int bf = *flag;
    int i = blockIdx.x * 256 + threadIdx.x;
    int d = i & 63;
    int f = (i >> 6) & 31;
    int b = i >> 11;
    float v = (f < 16) ? ldin(x,  ((size_t)b * 16 + f) * 64 + d, bf)
                       : ldin(xc, ((size_t)b * 16 + (f - 16)) * 64 + d, bf);
    X[i] = v;
}

// ---------------- LayerNorm 64 (fp32 + bf16 out) ----------------
__global__ __launch_bounds__(256) void k_ln64(const float* __restrict__ in,
                                              float* __restrict__ out,
                                              bf16* __restrict__ outh,
                                              const void* __restrict__ g,
                                              const void* __restrict__ b,
                                              size_t eoff,
                                              const int* __restrict__ flag) {
    const int bf = *flag;
    int row  = blockIdx.x * 4 + (threadIdx.x >> 6);
    int lane = threadIdx.x & 63;
    float v = in[(size_t)row * 64 + lane];
    float s = v;
    #pragma unroll
    for (int off = 32; off; off >>= 1) s += __shfl_xor(s, off);
    float mean = s * (1.0f / 64.0f);
    float dx = v - mean;
    float s2 = dx * dx;
    #pragma unroll
    for (int off = 32; off; off >>= 1) s2 += __shfl_xor(s2, off);
    float inv = rsqrtf(s2 * (1.0f / 64.0f) + LNEPS);
    float o = dx * inv * ldin(g, eoff + lane, bf) + ldin(b, eoff + lane, bf);
    out[(size_t)row * 64 + lane]  = o;
    outh[(size_t)row * 64 + lane] = __float2bfloat16(o);
}

// ---------------- LayerNorm 2048 (fp32 + bf16 out) ----------------
__global__ __launch_bounds__(256) void k_ln_row(const float* __restrict__ in,
                                                float* __restrict__ out,
                                                bf16* __restrict__ outh,
                                                const void* __restrict__ g,
                                                const void* __restrict__ b,
                                                size_t eoff,
                                                const int* __restrict__ flag) {
    const int bf = *flag;
    const int row = blockIdx.x, tid = threadIdx.x;
    __shared__ float red[4];
    const float* r = in + (size_t)row * DROW;
    float v[8];
    float s = 0.f;
    #pragma unroll
    for (int i = 0; i < 8; ++i) { v[i] = r[tid + i * 256]; s += v[i]; }
    #pragma unroll
    for (int off = 32; off; off >>= 1) s += __shfl_xor(s, off);
    if ((tid & 63) == 0) red[tid >> 6] = s;
    __syncthreads();
    float mean = (red[0] + red[1] + red[2] + red[3]) * (1.0f / DROW);
    __syncthreads();
    float s2 = 0.f;
    #pragma unroll
    for (int i = 0; i < 8; ++i) { float dx = v[i] - mean; s2 += dx * dx; }
    #pragma unroll
    for (int off = 32; off; off >>= 1) s2 += __shfl_xor(s2, off);
    if ((tid & 63) == 0) red[tid >> 6] = s2;
    __syncthreads();
    float inv = rsqrtf((red[0] + red[1] + red[2] + red[3]) * (1.0f / DROW) + LNEPS);
    #pragma unroll
    for (int i = 0; i < 8; ++i) {
        int j = tid + i * 256;
        float o = (v[i] - mean) * inv * ldin(g, eoff + j, bf) + ldin(b, eoff + j, bf);
        out[(size_t)row * DROW + j]  = o;
        outh[(size_t)row * DROW + j] = __float2bfloat16(o);
    }
}

// ---------------- transpose+cast weight ----------------
__global__ __launch_bounds__(256) void k_castT(const void* __restrict__ in, size_t eoff,
                                               int R, int C,
                                               bf16* __restrict__ out,
                                               const int* __restrict__ flag) {
    const int bf = *flag;
    __shared__ bf16 tile[32][33];
    const int tx = threadIdx.x & 31, ty = threadIdx.x >> 5;
    const int bx = blockIdx.x, by = blockIdx.y;
    #pragma unroll
    for (int k = 0; k < 4; ++k) {
        int r = bx * 32 + ty + k * 8;
        int c = by * 32 + tx;
        tile[ty + k * 8][tx] = __float2bfloat16(ldin(in, eoff + (size_t)r * C + c, bf));
    }
    __syncthreads();
    #pragma unroll
    for (int k = 0; k < 4; ++k) {
        int oc = by * 32 + ty + k * 8;
        int orr = bx * 32 + tx;
        out[(size_t)oc * R + orr] = tile[tx][ty + k * 8];
    }
}

// ---------------- plain cast (no transpose): bf16 copy of weight slice ----------------
__global__ __launch_bounds__(256) void k_cast_qkv(const void* __restrict__ in, size_t eoff,
                                                  bf16* __restrict__ out,
                                                  const int* __restrict__ flag) {
    const int bf = *flag;
    int i = blockIdx.x * 256 + threadIdx.x;
    out[i] = __float2bfloat16(ldin(in, eoff + i, bf));
}

// ---------------- transpose bf16 ----------------
__global__ __launch_bounds__(256) void k_transpose_bf(const bf16* __restrict__ in, int ld,
                                                      int R, int C,
                                                      bf16* __restrict__ out) {
    __shared__ bf16 tile[32][33];
    const int tx = threadIdx.x & 31, ty = threadIdx.x >> 5;
    const int bx = blockIdx.x, by = blockIdx.y;
    #pragma unroll
    for (int k = 0; k < 4; ++k) {
        int r = bx * 32 + ty + k * 8;
        int c = by * 32 + tx;
        tile[ty + k * 8][tx] = in[(size_t)r * ld + c];
    }
    __syncthreads();
    #pragma unroll
    for (int k = 0; k < 4; ++k) {
        int oc = by * 32 + ty + k * 8;
        int orr = bx * 32 + tx;
        out[(size_t)oc * R + orr] = tile[tx][ty + k * 8];
    }
}

// ---------------- MFMA GEMM split-K: z = K-chunk, fp32 partials ----------------
template <int WM, int WN>
__global__ __launch_bounds__(256) void k_mfma_sk(
    int M, int N, int KC,
    const bf16* __restrict__ A, int lda,
    const bf16* __restrict__ Bt, int ldb,
    float* __restrict__ Cp, long long pstride)
{
    constexpr int TM = WM * 64, TN = WN * 64;
    const int z = blockIdx.z;
    const int m0 = blockIdx.y * TM, n0 = blockIdx.x * TN;
    const int tid = threadIdx.x, lane = tid & 63, wave = tid >> 6;
    const int wy = wave / WN, wx = wave % WN;
    __shared__ short As[TM][72];
    __shared__ short Bs[TN][72];
    f32x4 acc[4][4] = {};
    const int row8 = tid >> 3, chunk = (tid & 7) * 8;
    const int kend = z * KC + KC;
    for (int k0 = z * KC; k0 < kend; k0 += 64) {
        #pragma unroll
        for (int i = 0; i < TM / 32; ++i) {
            int r = i * 32 + row8;
            *(short8*)&As[r][chunk] =
                *(const short8*)(A + (size_t)(m0 + r) * lda + k0 + chunk);
        }
        #pragma unroll
        for (int i = 0; i < TN / 32; ++i) {
            int r = i * 32 + row8;
            *(short8*)&Bs[r][chunk] =
                *(const short8*)(Bt + (size_t)(n0 + r) * ldb + k0 + chunk);
        }
        __syncthreads();
        #pragma unroll
        for (int ks = 0; ks < 64; ks += 32) {
            short8 af[4], bfr[4];
            #pragma unroll
            for (int mt = 0; mt < 4; ++mt)
                af[mt] = *(const short8*)&As[wy * 64 + mt * 16 + (lane & 15)][ks + (lane >> 4) * 8];
            #pragma unroll
            for (int nt = 0; nt < 4; ++nt)
                bfr[nt] = *(const short8*)&Bs[wx * 64 + nt * 16 + (lane & 15)][ks + (lane >> 4) * 8];
            #pragma unroll
            for (int mt = 0; mt < 4; ++mt)
                #pragma unroll
                for (int nt = 0; nt < 4; ++nt)
                    acc[mt][nt] = MFMA16(af[mt], bfr[nt], acc[mt][nt], 0, 0, 0);
        }
        __syncthreads();
    }
    float* Co = Cp + (size_t)z * pstride;
    #pragma unroll
    for (int mt = 0; mt < 4; ++mt)
        #pragma unroll
        for (int r = 0; r < 4; ++r) {
            int m = m0 + wy * 64 + mt * 16 + (lane >> 4) * 4 + r;
            #pragma unroll
            for (int nt = 0; nt < 4; ++nt) {
                int n = n0 + wx * 64 + nt * 16 + (lane & 15);
                Co[(size_t)m * N + n] = acc[mt][nt][r];
            }
        }
}

// ---------------- split-K combine (bf16 out; used for qkv) ----------------
template <bool OBF>
__global__ __launch_bounds__(256) void k_combine(
    int KS, const float* __restrict__ P, long long pstride, int N,
    void* __restrict__ C,
    const void* __restrict__ bias, size_t biasOff,
    const float* __restrict__ addend,
    const int* __restrict__ flag)
{
    int i = blockIdx.x * 256 + threadIdx.x;
    float v = 0.f;
    for (int z = 0; z < KS; ++z) v += P[(size_t)z * pstride + i];
    if (bias)   v += ldin(bias, biasOff + (size_t)(i % N), bias ? *flag : 0);
    if (addend) v += addend[i];
    if constexpr (OBF) ((bf16*)C)[i] = __float2bfloat16(v);
    else               ((float*)C)[i] = v;
}

// ---------------- fused: wo-combine + bias + residual + LayerNorm2048 ----------------
// XN(in) = r_ln1 out (residual addend); XN/XNh(out) = r_ln2 out. Same buffer is safe:
// every write data-depends (via mean/var) on all reads; blocks own disjoint rows.
__global__ __launch_bounds__(256) void k_comb_ln_row(
    const float* __restrict__ P, long long pstride,
    const void* __restrict__ bias, size_t biasOff,
    float* XN, bf16* __restrict__ XNh,
    const void* __restrict__ g, const void* __restrict__ b, size_t eoff,
    const int* __restrict__ flag)
{
    const int bf = *flag;
    const int row = blockIdx.x, tid = threadIdx.x;
    __shared__ float red[4];
    float v[8];
    float s = 0.f;
    #pragma unroll
    for (int i = 0; i < 8; ++i) {
        int j = tid + i * 256;
        size_t idx = (size_t)row * DROW + j;
        float t = P[idx] + P[pstride + idx] + P[2 * pstride + idx] + P[3 * pstride + idx];
        t += ldin(bias, biasOff + j, bf) + XN[idx];
        v[i] = t; s += t;
    }
    #pragma unroll
    for (int off = 32; off; off >>= 1) s += __shfl_xor(s, off);
    if ((tid & 63) == 0) red[tid >> 6] = s;
    __syncthreads();
    float mean = (red[0] + red[1] + red[2] + red[3]) * (1.0f / DROW);
    __syncthreads();
    float s2 = 0.f;
    #pragma unroll
    for (int i = 0; i < 8; ++i) { float dx = v[i] - mean; s2 += dx * dx; }
    #pragma unroll
    for (int off = 32; off; off >>= 1) s2 += __shfl_xor(s2, off);
    if ((tid & 63) == 0) red[tid >> 6] = s2;
    __syncthreads();
    float inv = rsqrtf((red[0] + red[1] + red[2] + red[3]) * (1.0f / DROW) + LNEPS);
    #pragma unroll
    for (int i = 0; i < 8; ++i) {
        int j = tid + i * 256;
        float o = (v[i] - mean) * inv * ldin(g, eoff + j, bf) + ldin(b, eoff + j, bf);
        XN[(size_t)row * DROW + j]  = o;
        XNh[(size_t)row * DROW + j] = __float2bfloat16(o);
    }
}

// ---------------- fused: w1-combine + bias + GEGLU ----------------
__global__ __launch_bounds__(256) void k_comb_geglu(
    const float* __restrict__ P, long long pstride,
    const void* __restrict__ b1, size_t b1Off,
    bf16* __restrict__ Out,
    const int* __restrict__ flag)
{
    const int bf = *flag;
    int i = blockIdx.x * 256 + threadIdx.x;   // 2048*1024
    int r = i >> 10, j = i & 1023;
    size_t ia = (size_t)r * 2048 + j, ig = ia + 1024;
    float a = P[ia] + P[pstride + ia] + P[2 * pstride + ia] + P[3 * pstride + ia]
            + ldin(b1, b1Off + j, bf);
    float gv = P[ig] + P[pstride + ig] + P[2 * pstride + ig] + P[3 * pstride + ig]
            + ldin(b1, b1Off + 1024 + j, bf);
    Out[i] = __float2bfloat16(a * gelu_exact(gv));
}

// ---------------- fused: w2-combine + bias + residual + LayerNorm64 (depth boundary) ----------------
__global__ __launch_bounds__(256) void k_comb_ln64(
    const float* __restrict__ P, long long pstride,
    const void* __restrict__ bias, size_t biasOff,   // r_b2, index mod 2048
    float* XN, bf16* __restrict__ XNh,
    const void* __restrict__ g, const void* __restrict__ b, size_t eoff,
    const int* __restrict__ flag)
{
    const int bf = *flag;
    int row  = blockIdx.x * 4 + (threadIdx.x >> 6);
    int lane = threadIdx.x & 63;
    size_t idx = (size_t)row * 64 + lane;
    float v = P[idx] + P[pstride + idx] + P[2 * pstride + idx] + P[3 * pstride + idx]
            + ldin(bias, biasOff + (idx & 2047), bf) + XN[idx];
    float s = v;
    #pragma unroll
    for (int off = 32; off; off >>= 1) s += __shfl_xor(s, off);
    float mean = s * (1.0f / 64.0f);
    float dx = v - mean;
    float s2 = dx * dx;
    #pragma unroll
    for (int off = 32; off; off >>= 1) s2 += __shfl_xor(s2, off);
    float inv = rsqrtf(s2 * (1.0f / 64.0f) + LNEPS);
    float o = dx * inv * ldin(g, eoff + lane, bf) + ldin(b, eoff + lane, bf);
    XN[idx]  = o;
    XNh[idx] = __float2bfloat16(o);
}

// ---------------- fused: w2-combine + bias + residual + output cast (d=3) ----------------
__global__ __launch_bounds__(256) void k_comb_cast(
    const float* __restrict__ P, long long pstride,
    const void* __restrict__ bias, size_t biasOff,
    const float* __restrict__ XN,
    void* __restrict__ out,
    const int* __restrict__ flag)
{
    const int bf = *flag;
    int i = blockIdx.x * 256 + threadIdx.x;
    float v = P[i] + P[(size_t)pstride + i] + P[2 * (size_t)pstride + i] + P[3 * (size_t)pstride + i]
            + ldin(bias, biasOff + (size_t)(i & 2047), bf) + XN[i];
    if (bf) ((bf16*)out)[i] = __float2bfloat16(v);
    else    ((float*)out)[i] = v;
}

// ---------------- per-head merged QK weight ----------------
// M_h[i][j] = sum_o Wq_h[i][o] * Wk_h[j][o]  (contraction over the HEAD-OUTPUT axis o).
// Source: Wh = non-transposed bf16 qkv weight [64 in][1536 out] — rows contiguous in o,
// exactly the MFMA fragment k-dim. Store Mt[h][j][i] = 0.125*M[i][j] (proj_tile B-layout).
__global__ __launch_bounds__(256) void k_qk_merge(
    const bf16* __restrict__ Wh,   // [64][1536]
    bf16* __restrict__ Mt)
{
    const int lane = threadIdx.x & 63, wave = threadIdx.x >> 6;
    const int h = blockIdx.x * 4 + wave;
    const int l15 = lane & 15, quad = lane >> 4;
    f32x4 acc[4][4] = {};
    #pragma unroll
    for (int kc = 0; kc < 2; ++kc) {
        short8 af[4], bfr[4];
        #pragma unroll
        for (int mt = 0; mt < 4; ++mt)
            af[mt] = *(const short8*)(Wh + (size_t)(mt * 16 + l15) * 1536 + h * 64 + kc * 32 + quad * 8);
        #pragma unroll
        for (int nt = 0; nt < 4; ++nt)
            bfr[nt] = *(const short8*)(Wh + (size_t)(nt * 16 + l15) * 1536 + 512 + h * 64 + kc * 32 + quad * 8);
        #pragma unroll
        for (int mt = 0; mt < 4; ++mt)
            #pragma unroll
            for (int nt = 0; nt < 4; ++nt)
                acc[mt][nt] = MFMA16(af[mt], bfr[nt], acc[mt][nt], 0, 0, 0);
    }
    // C-layout: row i = mt*16+quad*4+r, col j = nt*16+l15; store Mt[h][j][i] with 0.125 folded
    #pragma unroll
    for (int mt = 0; mt < 4; ++mt)
        #pragma unroll
        for (int nt = 0; nt < 4; ++nt)
            #pragma unroll
            for (int r = 0; r < 4; ++r)
                Mt[(size_t)h * 4096 + (nt * 16 + l15) * 64 + mt * 16 + quad * 4 + r] =
                    __float2bfloat16(acc[mt][nt][r] * 0.125f);
}

// ---------------- QKV projection sub-tile: c += X(32x64) @ W_h(64x64) ----------------
__device__ inline void proj_tile(const short8 xa[2][2], const bf16* __restrict__ wbase,
                                 int l15, int quad, f32x4 c[2][4]) {
    #pragma unroll
    for (int nt = 0; nt < 4; ++nt) {
        short8 b0 = *(const short8*)(wbase + (size_t)(nt * 16 + l15) * 64 + quad * 8);
        short8 b1 = *(const short8*)(wbase + (size_t)(nt * 16 + l15) * 64 + 32 + quad * 8);
        #pragma unroll
        for (int mt = 0; mt < 2; ++mt) {
            c[mt][nt] = MFMA16(xa[mt][0], b0, c[mt][nt], 0, 0, 0);
            c[mt][nt] = MFMA16(xa[mt][1], b1, c[mt][nt], 0, 0, 0);
        }
    }
}

// ---------------- fused col attention via merged-QK (per-wave LDS, no barriers) ----------------
// T = Xn @ Mt_h (replaces Q AND K projections); S = T @ Xn^T with B-operand = xa
// (rows-over-k fragments serve as either MFMA operand). V -> bufB transposed for
// single-b128 PV B-frags. No-max softmax (logits bounded), 1/rowsum after PV.
__global__ __launch_bounds__(256) void k_col_qkv_attn(
    const bf16* __restrict__ Xh, const bf16* __restrict__ Wt,
    const bf16* __restrict__ Mt, bf16* __restrict__ Oh)
{
    __shared__ __align__(16) short bufA[4][2304];   // T (32x72) -> P
    __shared__ __align__(16) short bufB[4][2304];   // V^T (64x36)
    const int tid = threadIdx.x, lane = tid & 63, wave = tid >> 6;
    const int task = blockIdx.x * 4 + wave;   // sample*8 + head
    const int s = task >> 3, h = task & 7;
    const int l15 = lane & 15, quad = lane >> 4;
    short* A  = bufA[wave];
    short* Bb = bufB[wave];

    short8 xa[2][2];
    #pragma unroll
    for (int mt = 0; mt < 2; ++mt)
        #pragma unroll
        for (int kc = 0; kc < 2; ++kc)
            xa[mt][kc] = *(const short8*)(Xh + (size_t)(s * 32 + mt * 16 + l15) * 64 + kc * 32 + quad * 8);

    // ---- T = Xn @ Mt_h -> A (C-layout, stride 72) ----
    {
        f32x4 c[2][4] = {};
        proj_tile(xa, Mt + (size_t)h * 4096, l15, quad, c);
        #pragma unroll
        for (int mt = 0; mt < 2; ++mt)
            #pragma unroll
            for (int nt = 0; nt < 4; ++nt)
                #pragma unroll
                for (int r = 0; r < 4; ++r)
                    *(bf16*)&A[(mt * 16 + quad * 4 + r) * 72 + nt * 16 + l15] =
                        __float2bfloat16(c[mt][nt][r]);
    }
    // ---- V -> Bb transposed ([64][36]) ----
    {
        f32x4 c[2][4] = {};
        proj_tile(xa, Wt + (size_t)(1024 + h * 64) * 64, l15, quad, c);
        #pragma unroll
        for (int mt = 0; mt < 2; ++mt)
            #pragma unroll
            for (int nt = 0; nt < 4; ++nt)
                #pragma unroll
                for (int r = 0; r < 4; ++r)
                    *(bf16*)&Bb[(nt * 16 + l15) * 36 + mt * 16 + quad * 4 + r] =
                        __float2bfloat16(c[mt][nt][r]);
    }
    // ---- S = T @ Xn^T (B-frags are xa) ----
    f32x4 S[2][2] = {};
    #pragma unroll
    for (int mt = 0; mt < 2; ++mt) {
        short8 ta0 = *(const short8*)&A[(mt * 16 + l15) * 72 + quad * 8];
        short8 ta1 = *(const short8*)&A[(mt * 16 + l15) * 72 + 32 + quad * 8];
        #pragma unroll
        for (int nt = 0; nt < 2; ++nt) {
            S[mt][nt] = MFMA16(ta0, xa[nt][0], S[mt][nt], 0, 0, 0);
            S[mt][nt] = MFMA16(ta1, xa[nt][1], S[mt][nt], 0, 0, 0);
        }
    }
    // ---- no-max softmax (scale folded into Mt); unnormalized P -> A ----
    float inv[2][4];
    #pragma unroll
    for (int mt = 0; mt < 2; ++mt) {
        #pragma unroll
        for (int ri = 0; ri < 4; ++ri) {
            float e0 = __expf(S[mt][0][ri]);
            float e1 = __expf(S[mt][1][ri]);
            float sum = e0 + e1;
            #pragma unroll
            for (int msk = 1; msk < 16; msk <<= 1) sum += __shfl_xor(sum, msk);
            inv[mt][ri] = 1.0f / sum;
            int row = mt * 16 + quad * 4 + ri;
            *(bf16*)&A[row * 72 + l15]      = __float2bfloat16(e0);
            *(bf16*)&A[row * 72 + 16 + l15] = __float2bfloat16(e1);
        }
    }
    // ---- O = P @ V, normalize ----
    short8 pa[2];
    #pragma unroll
    for (int mt = 0; mt < 2; ++mt)
        pa[mt] = *(const short8*)&A[(mt * 16 + l15) * 72 + quad * 8];
    f32x4 O[2][4] = {};
    #pragma unroll
    for (int nt = 0; nt < 4; ++nt) {
        short8 vb = *(const short8*)&Bb[(nt * 16 + l15) * 36 + quad * 8];
        #pragma unroll
        for (int mt = 0; mt < 2; ++mt)
            O[mt][nt] = MFMA16(pa[mt], vb, O[mt][nt], 0, 0, 0);
    }
    #pragma unroll
    for (int mt = 0; mt < 2; ++mt)
        #pragma unroll
        for (int nt = 0; nt < 4; ++nt)
            #pragma unroll
            for (int ri = 0; ri < 4; ++ri) {
                size_t row = (size_t)s * 32 + mt * 16 + quad * 4 + ri;
                Oh[row * 512 + h * 64 + nt * 16 + l15] =
                    __float2bfloat16(O[mt][nt][ri] * inv[mt][ri]);
            }
}

// ---------------- fused col wo-proj + bias + residual ----------------
__global__ __launch_bounds__(256) void k_col_wo(
    const bf16* __restrict__ Oh, const bf16* __restrict__ Wt,
    const void* __restrict__ bias, size_t biasOff,
    const float* __restrict__ XN, float* __restrict__ ACC,
    const int* __restrict__ flag)
{
    const int lane = threadIdx.x & 63, wave = threadIdx.x >> 6;
    const int rb = (blockIdx.x * 4 + wave) * 32;
    const int l15 = lane & 15, quad = lane >> 4;
    f32x4 acc[2][4] = {};
    #pragma unroll 2
    for (int kc = 0; kc < 512; kc += 32) {
        short8 a0 = *(const short8*)(Oh + (size_t)(rb + l15) * 512 + kc + quad * 8);
        short8 a1 = *(const short8*)(Oh + (size_t)(rb + 16 + l15) * 512 + kc + quad * 8);
        #pragma unroll
        for (int nt = 0; nt < 4; ++nt) {
            short8 b = *(const short8*)(Wt + (size_t)(nt * 16 + l15) * 512 + kc + quad * 8);
            acc[0][nt] = MFMA16(a0, b, acc[0][nt], 0, 0, 0);
            acc[1][nt] = MFMA16(a1, b, acc[1][nt], 0, 0, 0);
        }
    }
    const int bf = *flag;
    #pragma unroll
    for (int nt = 0; nt < 4; ++nt) {
        float bv = ldin(bias, biasOff + nt * 16 + l15, bf);
        #pragma unroll
        for (int mt = 0; mt < 2; ++mt)
            #pragma unroll
            for (int r = 0; r < 4; ++r) {
                size_t idx = (size_t)(rb + mt * 16 + quad * 4 + r) * 64 + nt * 16 + l15;
                ACC[idx] = acc[mt][nt][r] + bv + XN[idx];
            }
    }
}

// ---------------- fused col GEGLU MLP ----------------
__global__ __launch_bounds__(256) void k_col_mlp(
    const bf16* __restrict__ Xh,   // [65536][64] ln2 bf16
    const bf16* __restrict__ W1t,  // [512][64]
    const bf16* __restrict__ W2t,  // [64][256]
    const void* __restrict__ b1, size_t b1Off,
    const void* __restrict__ b2, size_t b2Off,
    const float* __restrict__ XN, float* __restrict__ Xout,
    const int* __restrict__ flag)
{
    __shared__ __align__(16) short Pl[4][32][72];
    const int lane = threadIdx.x & 63, wave = threadIdx.x >> 6;
    const int rb = (blockIdx.x * 4 + wave) * 32;
    const int l15 = lane & 15, quad = lane >> 4;
    const int bf = *flag;
    short (*P)[72] = Pl[wave];

    short8 xa[2][2];
    #pragma unroll
    for (int mt = 0; mt < 2; ++mt)
        #pragma unroll
        for (int kc = 0; kc < 2; ++kc)
            xa[mt][kc] = *(const short8*)(Xh + (size_t)(rb + mt * 16 + l15) * 64 + kc * 32 + quad * 8);

    f32x4 xacc[2][4] = {};
    #pragma unroll
    for (int jc = 0; jc < 256; jc += 64) {
        f32x4 ca[2][4] = {}, cg[2][4] = {};
        #pragma unroll
        for (int nt = 0; nt < 4; ++nt) {
            const bf16* wa = W1t + (size_t)(jc + nt * 16 + l15) * 64;
            short8 a0 = *(const short8*)(wa + quad * 8);
            short8 a1 = *(const short8*)(wa + 32 + quad * 8);
            const bf16* wg = W1t + (size_t)(256 + jc + nt * 16 + l15) * 64;
            short8 g0 = *(const short8*)(wg + quad * 8);
            short8 g1 = *(const short8*)(wg + 32 + quad * 8);
            #pragma unroll
            for (int mt = 0; mt < 2; ++mt) {
                ca[mt][nt] = MFMA16(xa[mt][0], a0, ca[mt][nt], 0, 0, 0);
                ca[mt][nt] = MFMA16(xa[mt][1], a1, ca[mt][nt], 0, 0, 0);
                cg[mt][nt] = MFMA16(xa[mt][0], g0, cg[mt][nt], 0, 0, 0);
                cg[mt][nt] = MFMA16(xa[mt][1], g1, cg[mt][nt], 0, 0, 0);
            }
        }
        #pragma unroll
        for (int nt = 0; nt < 4; ++nt) {
            float ba = ldin(b1, b1Off + jc + nt * 16 + l15, bf);
            float bg = ldin(b1, b1Off + 256 + jc + nt * 16 + l15, bf);
            #pragma unroll
            for (int mt = 0; mt < 2; ++mt)
                #pragma unroll
                for (int r = 0; r < 4; ++r) {
                    float p = (ca[mt][nt][r] + ba) * gelu_exact(cg[mt][nt][r] + bg);
                    *(bf16*)&P[mt * 16 + quad * 4 + r][nt * 16 + l15] = __float2bfloat16(p);
                }
        }
        short8 p0[2], p1[2];
        #pragma unroll
        for (int mt = 0; mt < 2; ++mt) {
            p0[mt] = *(const short8*)&P[mt * 16 + l15][quad * 8];
            p1[mt] = *(const short8*)&P[mt * 16 + l15][32 + quad * 8];
        }
        #pragma unroll
        for (int nt = 0; nt < 4; ++nt) {
            short8 w0 = *(const short8*)(W2t + (size_t)(nt * 16 + l15) * 256 + jc + quad * 8);
            short8 w1 = *(const short8*)(W2t + (size_t)(nt * 16 + l15) * 256 + jc + 32 + quad * 8);
            #pragma unroll
            for (int mt = 0; mt < 2; ++mt) {
                xacc[mt][nt] = MFMA16(p0[mt], w0, xacc[mt][nt], 0, 0, 0);
                xacc[mt][nt] = MFMA16(p1[mt], w1, xacc[mt][nt], 0, 0, 0);
            }
        }
    }
    #pragma unroll
    for (int nt = 0; nt < 4; ++nt) {
        float bv = ldin(b2, b2Off + nt * 16 + l15, bf);
        #pragma unroll
        for (int mt = 0; mt < 2; ++mt)
            #pragma unroll
            for (int r = 0; r < 4; ++r) {
                size_t idx = (size_t)(rb + mt * 16 + quad * 4 + r) * 64 + nt * 16 + l15;
                Xout[idx] = xacc[mt][nt][r] + bv + XN[idx];
            }
    }
}

// ---------------- flash row attention v2: K-split, barrier-free ----------------
__global__ __launch_bounds__(256) void k_flash_row(
    const bf16* __restrict__ QKV, const bf16* __restrict__ Vt,
    float* __restrict__ Opart, float* __restrict__ ML)
{
    __shared__ __align__(16) short Ps[4][16][136];
    const int tid = threadIdx.x, lane = tid & 63, wave = tid >> 6;
    const int h = blockIdx.y, z = blockIdx.z;
    const int q0 = blockIdx.x * 64 + wave * 16;
    const int l15 = lane & 15, quad = lane >> 4;

    short8 qa[2];
    #pragma unroll
    for (int kc = 0; kc < 2; ++kc)
        qa[kc] = *(const short8*)(QKV + (size_t)(q0 + l15) * 1536 + h * 64 + kc * 32 + quad * 8);

    float mi[4], li[4];
    #pragma unroll
    for (int r = 0; r < 4; ++r) { mi[r] = -1e30f; li[r] = 0.f; }
    f32x4 Oa[4] = {};

    #pragma unroll
    for (int jj = 0; jj < 4; ++jj) {
        const int j = z * 4 + jj;
        f32x4 s[8] = {};
        #pragma unroll
        for (int nt = 0; nt < 8; ++nt) {
            const bf16* krow = QKV + (size_t)(j * 128 + nt * 16 + l15) * 1536 + 512 + h * 64;
            short8 kb0 = *(const short8*)(krow + quad * 8);
            short8 kb1 = *(const short8*)(krow + 32 + quad * 8);
            s[nt] = MFMA16(qa[0], kb0, s[nt], 0, 0, 0);
            s[nt] = MFMA16(qa[1], kb1, s[nt], 0, 0, 0);
        }
        #pragma unroll
        for (int r = 0; r < 4; ++r) {
            float mt = -1e30f;
            #pragma unroll
            for (int nt = 0; nt < 8; ++nt) { s[nt][r] *= 0.125f; mt = fmaxf(mt, s[nt][r]); }
            #pragma unroll
            for (int msk = 1; msk < 16; msk <<= 1) mt = fmaxf(mt, __shfl_xor(mt, msk));
            float mn = fmaxf(mi[r], mt);
            float alpha = __expf(mi[r] - mn);
            float ls = 0.f;
            #pragma unroll
            for (int nt = 0; nt < 8; ++nt) { float p = __expf(s[nt][r] - mn); s[nt][r] = p; ls += p; }
            #pragma unroll
            for (int msk = 1; msk < 16; msk <<= 1) ls += __shfl_xor(ls, msk);
            li[r] = li[r] * alpha + ls;
            mi[r] = mn;
            #pragma unroll
            for (int nt = 0; nt < 4; ++nt) Oa[nt][r] *= alpha;
            int row = quad * 4 + r;
            #pragma unroll
            for (int nt = 0; nt < 8; ++nt)
                *(bf16*)&Ps[wave][row][nt * 16 + l15] = __float2bfloat16(s[nt][r]);
        }
        short8 pa[4];
        #pragma unroll
        for (int kc = 0; kc < 4; ++kc)
            pa[kc] = *(const short8*)&Ps[wave][l15][kc * 32 + quad * 8];
        #pragma unroll
        for (int nt = 0; nt < 4; ++nt) {
            #pragma unroll
            for (int kc = 0; kc < 4; ++kc) {
                short8 vb = *(const short8*)(Vt + (size_t)(h * 64 + nt * 16 + l15) * 2048 +
                                             j * 128 + kc * 32 + quad * 8);
                Oa[nt] = MFMA16(pa[kc], vb, Oa[nt], 0, 0, 0);
            }
        }
    }
    float* Op = Opart + (size_t)z * 1048576;
    #pragma unroll
    for (int nt = 0; nt < 4; ++nt)
        #pragma unroll
        for (int r = 0; r < 4; ++r)
            Op[(size_t)(q0 + quad * 4 + r) * 512 + h * 64 + nt * 16 + l15] = Oa[nt][r];
    if (l15 == 0) {
        #pragma unroll
        for (int r = 0; r < 4; ++r) {
            int row = q0 + quad * 4 + r;
            ML[((size_t)(z * 8 + h) * 2048 + row) * 2]     = mi[r];
            ML[((size_t)(z * 8 + h) * 2048 + row) * 2 + 1] = li[r];
        }
    }
}

// ---------------- flash combine ----------------
__global__ __launch_bounds__(256) void k_flash_combine(
    const float* __restrict__ Opart, const float* __restrict__ ML,
    bf16* __restrict__ O)
{
    int i = blockIdx.x * 256 + threadIdx.x;     // 2048*512
    int row = i >> 9, n = i & 511, h = n >> 6;
    float m[4], l[4], M = -1e30f;
    #pragma unroll
    for (int z = 0; z < 4; ++z) {
        m[z] = ML[((size_t)(z * 8 + h) * 2048 + row) * 2];
        l[z] = ML[((size_t)(z * 8 + h) * 2048 + row) * 2 + 1];
        M = fmaxf(M, m[z]);
    }
    float num = 0.f, den = 0.f;
    #pragma unroll
    for (int z = 0; z < 4; ++z) {
        float w = __expf(m[z] - M);
        num += w * Opart[(size_t)z * 1048576 + i];
        den += w * l[z];
    }
    O[i] = __float2bfloat16(num / den);
}

// =====================================================================
extern "C" void kernel_launch(void* const* d_in, const int* in_sizes, int n_in,
                              void* d_out, int out_size, void* d_ws, size_t ws_size,
                              hipStream_t stream) {
    const void* x       = d_in[0];
    const void* x_cont  = d_in[1];
    const void* c_ln1_g = d_in[2];
    const void* c_ln1_b = d_in[3];
    const void* c_wqkv  = d_in[4];
    const void* c_wo_w  = d_in[5];
    const void* c_wo_b  = d_in[6];
    const void* c_ln2_g = d_in[7];
    const void* c_ln2_b = d_in[8];
    const void* c_w1    = d_in[9];
    const void* c_b1    = d_in[10];
    const void* c_w2    = d_in[11];
    const void* c_b2    = d_in[12];
    const void* r_ln1_g = d_in[13];
    const void* r_ln1_b = d_in[14];
    const void* r_wqkv  = d_in[15];
    const void* r_wo_w  = d_in[16];
    const void* r_wo_b  = d_in[17];
    const void* r_ln2_g = d_in[18];
    const void* r_ln2_b = d_in[19];
    const void* r_w1    = d_in[20];
    const void* r_b1    = d_in[21];
    const void* r_w2    = d_in[22];
    const void* r_b2    = d_in[23];

    const size_t NX = (size_t)BD * NF * DIMC;        // 4,194,304
    float* X   = (float*)d_ws;
    float* XN  = X   + NX;
    float* ACC = XN  + NX;
    bf16* XNh  = (bf16*)(ACC + NX);
    bf16* WtR  = XNh + NX;                            // <=2048x2048
    bf16* WcQ  = WtR + (size_t)2048 * 2048;           // 1536x64 (transposed; V path)
    bf16* WcO  = WcQ + 98304;                         // 64x512
    bf16* Wc1  = WcO + 32768;                         // 512x64
    bf16* Wc2  = Wc1 + 32768;                         // 64x256
    bf16* McQ  = Wc2 + 16384;                         // 8x64x64 merged QK
    bf16* WqkvH= McQ + 32768;                         // 64x1536 non-transposed bf16 qkv
    bf16* Sc   = WqkvH + 98304;                       // scratch union base

    // col block overlays:
    bf16*  OhC  = Sc;                                         // [0, 64 MiB)
    // row block overlays:
    bf16*  QKVhR = Sc;                                        // 6.3MB
    bf16*  VtR   = QKVhR + 3145728;                           // 2.1MB
    bf16*  OhR   = VtR + 1048576;                             // 2.1MB
    bf16*  PmR   = OhR + 1048576;                             // 4.2MB
    float* GpR   = (float*)((char*)Sc + 33554432);            // row partials (ends 96 MiB)
    float* MLp   = GpR + (size_t)4 * 1048576;                 // flash m/l (1MB; qkv partials dead then)

    char* scEnd = (char*)Sc + 100663296;                      // 96 MiB
    int*  flag  = (int*)scEnd;
    const size_t need = (size_t)(scEnd + 64 - (char*)d_ws);
    if (ws_size < need) return;

    k_detect<<<1, 64, 0, stream>>>(x, flag);
    k_concat<<<16384, 256, 0, stream>>>(x, x_cont, X, flag);
    // col ln1 for d=0 (subsequent depth boundaries fuse it into k_comb_ln64)
    k_ln64<<<16384, 256, 0, stream>>>(X, XN, XNh, c_ln1_g, c_ln1_b, 0, flag);

    for (int d = 0; d < 4; ++d) {
        // ================= col block =================
        k_castT<<<dim3(2, 48), 256, 0, stream>>>(c_wqkv, (size_t)d * 64 * 1536, 64, 1536, WcQ, flag);
        k_cast_qkv<<<384, 256, 0, stream>>>(c_wqkv, (size_t)d * 64 * 1536, WqkvH, flag);
        k_qk_merge<<<2, 256, 0, stream>>>(WqkvH, McQ);
        k_col_qkv_attn<<<4096, 256, 0, stream>>>(XNh, WcQ, McQ, OhC);
        k_castT<<<dim3(16, 2), 256, 0, stream>>>(c_wo_w, (size_t)d * 512 * 64, 512, 64, WcO, flag);
        k_col_wo<<<512, 256, 0, stream>>>(OhC, WcO, c_wo_b, (size_t)d * 64, XN, ACC, flag);
        k_ln64<<<16384, 256, 0, stream>>>(ACC, XN, XNh, c_ln2_g, c_ln2_b, (size_t)d * 64, flag);
        k_castT<<<dim3(2, 16), 256, 0, stream>>>(c_w1, (size_t)d * 64 * 512, 64, 512, Wc1, flag);
        k_castT<<<dim3(8, 2), 256, 0, stream>>>(c_w2, (size_t)d * 256 * 64, 256, 64, Wc2, flag);
        k_col_mlp<<<512, 256, 0, stream>>>(XNh, Wc1, Wc2,
                                           c_b1, (size_t)d * 512, c_b2, (size_t)d * 64,
                                           XN, X, flag);

        // ================= row block =================
        k_ln_row<<<BD, 256, 0, stream>>>(X, XN, XNh, r_ln1_g, r_ln1_b, (size_t)d * DROW, flag);
        // QKVhR = XNh @ r_wqkv  (split-K=4, bf16 out)
        k_castT<<<dim3(64, 48), 256, 0, stream>>>(r_wqkv, (size_t)d * 2048 * 1536, 2048, 1536, WtR, flag);
        k_mfma_sk<2, 2><<<dim3(12, 16, 4), 256, 0, stream>>>(
            2048, 1536, 512, XNh, 2048, WtR, 2048, GpR, 3145728);
        k_combine<true><<<12288, 256, 0, stream>>>(
            4, GpR, 3145728, 1536, QKVhR, nullptr, 0, nullptr, flag);
        k_transpose_bf<<<dim3(64, 16), 256, 0, stream>>>(QKVhR + 1024, 1536, 2048, 512, VtR);
        // flash attention (K-split z=4) + combine
        k_flash_row<<<dim3(32, 8, 4), 256, 0, stream>>>(QKVhR, VtR, GpR, MLp);
        k_flash_combine<<<4096, 256, 0, stream>>>(GpR, MLp, OhR);
        // wo GEMM -> partials; fused combine+bias+residual+ln2
        k_castT<<<dim3(16, 64), 256, 0, stream>>>(r_wo_w, (size_t)d * 512 * 2048, 512, 2048, WtR, flag);
        k_mfma_sk<2, 2><<<dim3(16, 16, 4), 256, 0, stream>>>(
            2048, 2048, 128, OhR, 512, WtR, 512, GpR, 4194304);
        k_comb_ln_row<<<BD, 256, 0, stream>>>(
            GpR, 4194304, r_wo_b, (size_t)d * DROW, XN, XNh,
            r_ln2_g, r_ln2_b, (size_t)d * DROW, flag);
        // w1 GEMM -> partials; fused combine+bias+geglu
        k_castT<<<dim3(64, 64), 256, 0, stream>>>(r_w1, (size_t)d * 2048 * 2048, 2048, 2048, WtR, flag);
        k_mfma_sk<2, 2><<<dim3(16, 16, 4), 256, 0, stream>>>(
            2048, 2048, 512, XNh, 2048, WtR, 2048, GpR, 4194304);
        k_comb_geglu<<<8192, 256, 0, stream>>>(GpR, 4194304, r_b1, (size_t)d * 2048, PmR, flag);
        // w2 GEMM -> partials; fused combine + (next-depth col ln1 | output cast)
        k_castT<<<dim3(32, 64), 256, 0, stream>>>(r_w2, (size_t)d * 1024 * 2048, 1024, 2048, WtR, flag);
        k_mfma_sk<2, 2><<<dim3(16, 16, 4), 256, 0, stream>>>(
            2048, 2048, 256, PmR, 1024, WtR, 1024, GpR, 4194304);
        if (d < 3)
            k_comb_ln64<<<16384, 256, 0, stream>>>(
                GpR, 4194304, r_b2, (size_t)d * DROW, XN, XNh,
                c_ln1_g, c_ln1_b, (size_t)(d + 1) * 64, flag);
        else
            k_comb_cast<<<16384, 256, 0, stream>>>(
                GpR, 4194304, r_b2, (size_t)d * DROW, XN, d_out, flag);
    }
}